// Round 7
// baseline (475.858 us; speedup 1.0000x reference)
//
#include <hip/hip_runtime.h>
#include <math.h>

#define N_NODES 50000
#define N_EDGES 1000000
#define HID 64
#define CAP 64                          // slots per node (P(deg>=64) ~ 1e-10 for this input)
#define N_TILES (N_NODES / 16)          // 3125
#define NB_MLP 782                      // layer blocks: 782*4 waves = 3128 >= 3125 tiles (1 tile/wave)
#define VB_S 72                         // vb row stride (ushorts)
#define UB_S 136                        // ub row stride (ushorts)
#define NB_ENC ((N_NODES + 3) / 4)      // 12500
#define NB_WPREP ((3 * 8192 + 255) / 256) // 96
#define NBK 196                         // coarse buckets = dst>>8 (50000>>8 = 195)
#define BKCAP 6144                      // bucket capacity (mean 5120, +14 sigma)
#define EPB 4096                        // edges per pass-1 block
#define NB1 ((N_EDGES + EPB - 1) / EPB) // 245
static_assert(N_NODES % 16 == 0, "tile math");
static_assert(N_NODES <= 65536, "src must fit in 16 bits");

typedef __attribute__((ext_vector_type(8))) short short8;   // 8 bf16 = 4 VGPRs
typedef __attribute__((ext_vector_type(4))) float f32x4;

__device__ __forceinline__ unsigned short f2bf(float x) {   // RNE float->bf16
    unsigned u = __float_as_uint(x);
    u += 0x7FFFu + ((u >> 16) & 1u);
    return (unsigned short)(u >> 16);
}
__device__ __forceinline__ float bfbits_hi(unsigned pk) {
    return __uint_as_float(pk & 0xFFFF0000u);
}
__device__ __forceinline__ float bf2f(unsigned short v) {
    return __uint_as_float(((unsigned)v) << 16);
}
__device__ __forceinline__ unsigned addpk(unsigned a, unsigned b) {
    float lo = __uint_as_float(a << 16) + __uint_as_float(b << 16);
    float hi = __uint_as_float(a & 0xFFFF0000u) + __uint_as_float(b & 0xFFFF0000u);
    return (unsigned)f2bf(lo) | ((unsigned)f2bf(hi) << 16);
}

// ---------------- fused front: bin1 coarse scatter | node encoder | weight prep ----------------
__global__ __launch_bounds__(256) void k_front(
    const float* __restrict__ x, const float* __restrict__ Wn,
    const float* __restrict__ bn, unsigned short* __restrict__ zb,
    const float* __restrict__ W1, const float* __restrict__ W2,
    unsigned short* __restrict__ w1p, unsigned short* __restrict__ w2p,
    const int* __restrict__ ei, const float* __restrict__ eattr,
    int* __restrict__ gcnt, uint2* __restrict__ coarse) {
    __shared__ unsigned pk_l[EPB];          // 16 KB
    __shared__ unsigned short dst_l[EPB];   // 8 KB
    __shared__ unsigned spk[EPB];           // 16 KB (bucket-sorted)
    __shared__ unsigned short sdst[EPB];    // 8 KB
    __shared__ int hist[NBK], loc[NBK], gbase[NBK], cur[NBK];
    __shared__ int inc[256];
    int b = blockIdx.x;
    if (b < NB1) {
        // pass 1: LDS-binned coarse scatter (dst>>8 buckets)
        int tid = threadIdx.x;
        int e0 = b * EPB;
        int nel = N_EDGES - e0; if (nel > EPB) nel = EPB;
        for (int q = tid; q < NBK; q += 256) { hist[q] = 0; cur[q] = 0; }
        __syncthreads();
        for (int j = tid; j < nel; j += 256) {
            int i = e0 + j;
            int d = ei[N_EDGES + i];
            unsigned pk = ((unsigned)f2bf(eattr[i]) << 16) | (unsigned)(ei[i] & 0xFFFF);
            pk_l[j] = pk; dst_l[j] = (unsigned short)d;
            atomicAdd(&hist[d >> 8], 1);
        }
        __syncthreads();
        int v = (tid < NBK) ? hist[tid] : 0;
        inc[tid] = v;
        __syncthreads();
        #pragma unroll
        for (int dd = 1; dd < 256; dd <<= 1) {
            int t2 = (tid >= dd) ? inc[tid - dd] : 0;
            __syncthreads();
            inc[tid] += t2;
            __syncthreads();
        }
        if (tid < NBK) {
            loc[tid] = inc[tid] - v;                     // exclusive local offset
            gbase[tid] = atomicAdd(&gcnt[tid], v);       // reserve bucket space
        }
        __syncthreads();
        // local counting sort by bucket
        for (int j = tid; j < nel; j += 256) {
            int bkt = dst_l[j] >> 8;
            int r = atomicAdd(&cur[bkt], 1);
            int pos = loc[bkt] + r;
            spk[pos] = pk_l[j]; sdst[pos] = dst_l[j];
        }
        __syncthreads();
        // write out: consecutive j within a bucket run -> consecutive global addresses
        for (int j = tid; j < nel; j += 256) {
            int d = sdst[j];
            int bkt = d >> 8;
            int off = gbase[bkt] + (j - loc[bkt]);
            if (off < BKCAP) coarse[(size_t)bkt * BKCAP + off] = make_uint2(spk[j], (unsigned)d);
        }
    } else if (b < NB1 + NB_ENC) {
        // node encoder: zb = bf16(x @ W_node + b_node)
        int n = (b - NB1) * 4 + (threadIdx.x >> 6);
        int c = threadIdx.x & 63;
        if (n >= N_NODES) return;
        float acc = bn[c];
        const float* xr = x + n * 16;
        #pragma unroll
        for (int k = 0; k < 16; ++k) acc = fmaf(xr[k], Wn[k * 64 + c], acc);
        zb[n * 64 + c] = f2bf(acc);
    } else {
        // weight prep: pack W1/W2 (3 layers) into bf16 fragment order
        int i = (b - NB1 - NB_ENC) * 256 + threadIdx.x;
        if (i >= 3 * 8192) return;
        int L = i >> 13, r = i & 8191;
        int j = r & 7, lane = (r >> 3) & 63;
        int quad = lane >> 4, col = lane & 15;
        {
            int st = r >> 9;                 // s=st>>3 (2), t=st&7 (8)
            int s = st >> 3, t = st & 7;
            w1p[i] = f2bf(W1[L * 8192 + (s * 32 + quad * 8 + j) * 128 + t * 16 + col]);
        }
        {
            int ft = r >> 9;                 // s=ft>>2 (4), t=ft&3 (4)
            int s = ft >> 2, t = ft & 3;
            w2p[i] = f2bf(W2[L * 8192 + (s * 32 + quad * 8 + j) * 64 + t * 16 + col]);
        }
    }
}

// ---------------- pass 2: per-half-bucket fine CSR built in LDS -> CAP-slotted s_pack --------
// 392 blocks: block handles bucket b>>1, node-halves (b&1)*128..+127
__global__ __launch_bounds__(256) void k_bin2(
    const int* __restrict__ gcnt, const uint2* __restrict__ coarse,
    int* __restrict__ cnt, unsigned int* __restrict__ s_pack) {
    __shared__ unsigned epk[BKCAP];          // 24 KB
    __shared__ unsigned char eln[BKCAP];     // 6 KB
    __shared__ unsigned spk[BKCAP];          // 24 KB (node-sorted, in-range only)
    __shared__ unsigned char sln[BKCAP];     // 6 KB
    __shared__ int hist[128], loc[128], cur[128], inc2[128];
    int tid = threadIdx.x;
    int bkt = blockIdx.x >> 1;
    int hsel = blockIdx.x & 1;               // ln half select (ln>>7)
    int m = gcnt[bkt]; if (m > BKCAP) m = BKCAP;
    if (tid < 128) { hist[tid] = 0; cur[tid] = 0; }
    __syncthreads();
    for (int j = tid; j < m; j += 256) {
        uint2 e = coarse[(size_t)bkt * BKCAP + j];
        epk[j] = e.x;
        int ln = (int)(e.y & 255u);
        eln[j] = (unsigned char)ln;
        if ((ln >> 7) == hsel) atomicAdd(&hist[ln & 127], 1);
    }
    __syncthreads();
    int v = (tid < 128) ? hist[tid] : 0;
    if (tid < 128) inc2[tid] = v;
    __syncthreads();
    #pragma unroll
    for (int dd = 1; dd < 128; dd <<= 1) {
        int t2 = (tid >= dd && tid < 128) ? inc2[tid - dd] : 0;
        __syncthreads();
        if (tid < 128) inc2[tid] += t2;
        __syncthreads();
    }
    if (tid < 128) {
        loc[tid] = inc2[tid] - v;            // exclusive
        int node = bkt * 256 + hsel * 128 + tid;
        if (node < N_NODES) cnt[node] = v;
    }
    __syncthreads();
    int mh = inc2[127];                      // in-range edge count
    for (int j = tid; j < m; j += 256) {
        int ln = eln[j];
        if ((ln >> 7) == hsel) {
            int r = atomicAdd(&cur[ln & 127], 1);
            int pos = loc[ln & 127] + r;
            spk[pos] = epk[j]; sln[pos] = (unsigned char)ln;
        }
    }
    __syncthreads();
    for (int j = tid; j < mh; j += 256) {
        int ln = sln[j];
        int k = j - loc[ln & 127];
        if (k < CAP) s_pack[(size_t)(bkt * 256 + ln) * CAP + k] = spk[j];
    }
}

// ---------------- fused layer: per wave = 1 tile (agg 16 nodes -> MFMA MLP) ----------------
// agg: lanes 0-31 even edge, 32-63 odd edge, lane owns channels {2c2,2c2+1}; result -> own LDS vb.
// mlp: per-wave 16x64 tile; weights read per-wave from L2-hot packed buffers (no weight LDS).
// z double-buffered across layers (zin gathered by all blocks; zout written per-tile).
__global__ __launch_bounds__(256) void k_layer(
    const unsigned short* __restrict__ zin, unsigned short* __restrict__ zout,
    unsigned short* __restrict__ hb,
    const int* __restrict__ cnt, const unsigned int* __restrict__ s_pack,
    const float* __restrict__ We, const float* __restrict__ be,
    const float* __restrict__ t, int layer,
    const unsigned short* __restrict__ w1p, const unsigned short* __restrict__ w2p,
    const float* __restrict__ b1,
    const float* __restrict__ g1, const float* __restrict__ be1,
    const float* __restrict__ b2,
    const float* __restrict__ ng, const float* __restrict__ nb, int mode,
    float* __restrict__ pb_sum, float* __restrict__ pb_max) {
    __shared__ unsigned short vbuf[4][16 * VB_S];
    __shared__ unsigned short ubuf[4][16 * UB_S];
    __shared__ float lssum[4][4][16], lsmax[4][4][16];
    int lane = threadIdx.x & 63;
    int wave = threadIdx.x >> 6;
    int col = lane & 15, quad = lane >> 4;
    unsigned short* vb = vbuf[wave];
    unsigned short* ub = ubuf[wave];
    int tile = blockIdx.x * 4 + wave;
    float psum[4] = {0.f, 0.f, 0.f, 0.f};
    float pmax[4] = {0.f, 0.f, 0.f, 0.f};

    if (tile < N_TILES) {
        int n0 = tile * 16;
        // ---------- agg phase: 16 nodes sequentially ----------
        {
            int half = lane >> 5;
            int c2 = lane & 31;
            float we0 = We[2 * c2], we1 = We[2 * c2 + 1];
            float bv0 = be[2 * c2], bv1 = be[2 * c2 + 1];
            float tl = t[layer];
            const unsigned* zbu = (const unsigned*)zin;
            for (int ln = 0; ln < 16; ++ln) {
                int wid = n0 + ln;
                int deg = cnt[wid];
                deg = (deg < CAP) ? deg : CAP;
                int beg = wid * CAP, end = beg + deg;
                float s0 = 0.f, s1 = 0.f, nn0 = 0.f, nn1 = 0.f;
                int i = beg;
                for (; i + 7 < end; i += 8) {
                    unsigned pk[4];
                    #pragma unroll
                    for (int j = 0; j < 4; ++j) {
                        unsigned pa = s_pack[i + 2 * j];
                        unsigned pb = s_pack[i + 2 * j + 1];
                        pk[j] = half ? pb : pa;
                    }
                    unsigned zu[4];
                    #pragma unroll
                    for (int j = 0; j < 4; ++j) zu[j] = zbu[(pk[j] & 0xFFFFu) * 32 + c2];
                    #pragma unroll
                    for (int j = 0; j < 4; ++j) {
                        float ea = bfbits_hi(pk[j]);
                        float z0 = __uint_as_float(zu[j] << 16);
                        float z1 = __uint_as_float(zu[j] & 0xFFFF0000u);
                        float m0 = fmaxf(z0 + fmaf(ea, we0, bv0), 0.f) + 1e-7f;
                        float m1 = fmaxf(z1 + fmaf(ea, we1, bv1), 0.f) + 1e-7f;
                        float p0 = __expf(m0 * tl), p1 = __expf(m1 * tl);
                        s0 += p0; nn0 = fmaf(p0, m0, nn0);
                        s1 += p1; nn1 = fmaf(p1, m1, nn1);
                    }
                }
                for (; i + 1 < end; i += 2) {
                    unsigned pa = s_pack[i], pb = s_pack[i + 1];
                    unsigned pk = half ? pb : pa;
                    unsigned zu = zbu[(pk & 0xFFFFu) * 32 + c2];
                    float ea = bfbits_hi(pk);
                    float z0 = __uint_as_float(zu << 16);
                    float z1 = __uint_as_float(zu & 0xFFFF0000u);
                    float m0 = fmaxf(z0 + fmaf(ea, we0, bv0), 0.f) + 1e-7f;
                    float m1 = fmaxf(z1 + fmaf(ea, we1, bv1), 0.f) + 1e-7f;
                    float p0 = __expf(m0 * tl), p1 = __expf(m1 * tl);
                    s0 += p0; nn0 = fmaf(p0, m0, nn0);
                    s1 += p1; nn1 = fmaf(p1, m1, nn1);
                }
                if (i < end) {             // single leftover: lo half only
                    unsigned pk = s_pack[i];
                    unsigned zu = zbu[(pk & 0xFFFFu) * 32 + c2];
                    float ea = bfbits_hi(pk);
                    float z0 = __uint_as_float(zu << 16);
                    float z1 = __uint_as_float(zu & 0xFFFF0000u);
                    float m0 = fmaxf(z0 + fmaf(ea, we0, bv0), 0.f) + 1e-7f;
                    float m1 = fmaxf(z1 + fmaf(ea, we1, bv1), 0.f) + 1e-7f;
                    float p0 = __expf(m0 * tl), p1 = __expf(m1 * tl);
                    if (half == 0) {
                        s0 += p0; nn0 = fmaf(p0, m0, nn0);
                        s1 += p1; nn1 = fmaf(p1, m1, nn1);
                    }
                }
                s0 += __shfl_xor(s0, 32, 64); nn0 += __shfl_xor(nn0, 32, 64);
                s1 += __shfl_xor(s1, 32, 64); nn1 += __shfl_xor(nn1, 32, 64);
                if (half == 0) {
                    unsigned r = (unsigned)f2bf(nn0 / (s0 + 1e-16f)) |
                                 ((unsigned)f2bf(nn1 / (s1 + 1e-16f)) << 16);
                    *(unsigned*)&vb[ln * VB_S + 2 * c2] = r;      // agg row -> own LDS
                }
            }
        }
        // ---------- mlp phase (per-wave tile) ----------
        int nd = lane >> 2;
        int cg = (lane & 3) * 16;
        uint4* vdst = (uint4*)&vb[nd * VB_S + cg];
        {
            const uint4* zp = (const uint4*)(zin + (size_t)(n0 + nd) * 64 + cg);
            uint4 z0 = zp[0], z1 = zp[1];
            uint4 a0 = vdst[0], a1 = vdst[1];            // agg from LDS
            uint4 r0, r1;
            r0.x = addpk(a0.x, z0.x); r0.y = addpk(a0.y, z0.y);
            r0.z = addpk(a0.z, z0.z); r0.w = addpk(a0.w, z0.w);
            r1.x = addpk(a1.x, z1.x); r1.y = addpk(a1.y, z1.y);
            r1.z = addpk(a1.z, z1.z); r1.w = addpk(a1.w, z1.w);
            vdst[0] = r0; vdst[1] = r1;
        }
        short8 af0 = *(const short8*)&vb[col * VB_S + quad * 8];
        short8 af1 = *(const short8*)&vb[col * VB_S + 32 + quad * 8];

        uint4 h0, h1;
        if (mode >= 1) {
            const uint4* hp = (const uint4*)(hb + (size_t)(n0 + nd) * 64 + cg);
            h0 = hp[0]; h1 = hp[1];
        }

        float b1f[8], g1f[8], e1f[8];
        #pragma unroll
        for (int tt = 0; tt < 8; ++tt) {
            int ch = tt * 16 + col;
            b1f[tt] = b1[ch]; g1f[tt] = g1[ch]; e1f[tt] = be1[ch];
        }
        float b2f_[4], ngf[4], nbf[4];
        #pragma unroll
        for (int tt = 0; tt < 4; ++tt) {
            b2f_[tt] = b2[tt * 16 + col];
            ngf[tt] = ng[tt * 16 + col];
            nbf[tt] = nb[tt * 16 + col];
        }

        f32x4 au[8];
        #pragma unroll
        for (int tt = 0; tt < 8; ++tt) {
            short8 w0 = *(const short8*)&w1p[((0 * 8 + tt) * 64 + lane) * 8];
            short8 w1 = *(const short8*)&w1p[((1 * 8 + tt) * 64 + lane) * 8];
            f32x4 c = {0.f, 0.f, 0.f, 0.f};
            c = __builtin_amdgcn_mfma_f32_16x16x32_bf16(af0, w0, c, 0, 0, 0);
            c = __builtin_amdgcn_mfma_f32_16x16x32_bf16(af1, w1, c, 0, 0, 0);
            au[tt] = c;
        }
        #pragma unroll
        for (int r = 0; r < 4; ++r) {
            float sx = 0.f, sq = 0.f;
            #pragma unroll
            for (int tt = 0; tt < 8; ++tt) {
                float v = au[tt][r] + b1f[tt];
                sx += v; sq += v * v;
            }
            #pragma unroll
            for (int mask = 1; mask < 16; mask <<= 1) {
                sx += __shfl_xor(sx, mask, 64);
                sq += __shfl_xor(sq, mask, 64);
            }
            float mu = sx * (1.f / 128.f);
            float var = sq * (1.f / 128.f) - mu * mu;
            float rs = rsqrtf(var + 1e-5f);
            int row = quad * 4 + r;
            #pragma unroll
            for (int tt = 0; tt < 8; ++tt) {
                float v = au[tt][r] + b1f[tt];
                float y = fmaxf(fmaf((v - mu) * rs, g1f[tt], e1f[tt]), 0.f);
                ub[row * UB_S + tt * 16 + col] = f2bf(y);
            }
        }
        f32x4 oc[4];
        #pragma unroll
        for (int tt = 0; tt < 4; ++tt) oc[tt] = (f32x4){0.f, 0.f, 0.f, 0.f};
        #pragma unroll
        for (int s = 0; s < 4; ++s) {
            short8 a = *(const short8*)&ub[col * UB_S + s * 32 + quad * 8];
            #pragma unroll
            for (int tt = 0; tt < 4; ++tt) {
                short8 w = *(const short8*)&w2p[((s * 4 + tt) * 64 + lane) * 8];
                oc[tt] = __builtin_amdgcn_mfma_f32_16x16x32_bf16(a, w, oc[tt], 0, 0, 0);
            }
        }
        if (mode >= 1) {
            vdst[0] = h0; vdst[1] = h1;                  // h residual into vb
        }
        #pragma unroll
        for (int r = 0; r < 4; ++r) {
            int row = quad * 4 + r;
            float val[4];
            #pragma unroll
            for (int tt = 0; tt < 4; ++tt) {
                val[tt] = oc[tt][r] + b2f_[tt];
                if (mode >= 1) val[tt] += bf2f(vb[row * VB_S + tt * 16 + col]);
            }
            float sx = 0.f, sq = 0.f;
            #pragma unroll
            for (int tt = 0; tt < 4; ++tt) { sx += val[tt]; sq += val[tt] * val[tt]; }
            #pragma unroll
            for (int mask = 1; mask < 16; mask <<= 1) {
                sx += __shfl_xor(sx, mask, 64);
                sq += __shfl_xor(sq, mask, 64);
            }
            float mu = sx * (1.f / 64.f);
            float var = sq * (1.f / 64.f) - mu * mu;
            float rs = rsqrtf(var + 1e-5f);
            #pragma unroll
            for (int tt = 0; tt < 4; ++tt) {
                float y = fmaxf(fmaf((val[tt] - mu) * rs, ngf[tt], nbf[tt]), 0.f);
                if (mode <= 1) {
                    vb[row * VB_S + tt * 16 + col] = f2bf(val[tt]);   // h
                    ub[row * UB_S + tt * 16 + col] = f2bf(y);         // z
                } else {
                    psum[tt] += y;
                    pmax[tt] = fmaxf(pmax[tt], y);
                }
            }
        }
        if (mode <= 1) {
            const uint4* hsrc = (const uint4*)&vb[nd * VB_S + cg];
            const uint4* zsrc = (const uint4*)&ub[nd * UB_S + cg];
            uint4* hdst = (uint4*)(hb + (size_t)(n0 + nd) * 64 + cg);
            uint4* zdst = (uint4*)(zout + (size_t)(n0 + nd) * 64 + cg);
            hdst[0] = hsrc[0]; hdst[1] = hsrc[1];
            zdst[0] = zsrc[0]; zdst[1] = zsrc[1];
        }
    }
    if (mode == 2) {
        #pragma unroll
        for (int tt = 0; tt < 4; ++tt) {
            psum[tt] += __shfl_xor(psum[tt], 16, 64);
            psum[tt] += __shfl_xor(psum[tt], 32, 64);
            pmax[tt] = fmaxf(pmax[tt], __shfl_xor(pmax[tt], 16, 64));
            pmax[tt] = fmaxf(pmax[tt], __shfl_xor(pmax[tt], 32, 64));
        }
        if (quad == 0) {
            #pragma unroll
            for (int tt = 0; tt < 4; ++tt) {
                lssum[wave][tt][col] = psum[tt];
                lsmax[wave][tt][col] = pmax[tt];
            }
        }
        __syncthreads();
        if (wave == 0) {
            int tt = lane >> 4, c = lane & 15;
            float s = lssum[0][tt][c] + lssum[1][tt][c] + lssum[2][tt][c] + lssum[3][tt][c];
            float mx = fmaxf(fmaxf(lsmax[0][tt][c], lsmax[1][tt][c]),
                             fmaxf(lsmax[2][tt][c], lsmax[3][tt][c]));
            pb_sum[blockIdx.x * 64 + lane] = s;
            pb_max[blockIdx.x * 64 + lane] = mx;
        }
    }
}

// ---------------- head: full partial reduction + pooling + linear ----------------
__global__ __launch_bounds__(1024) void k_head(
    const float* __restrict__ pb_sum, const float* __restrict__ pb_max,
    const float* __restrict__ Wl, const float* __restrict__ bl, float* __restrict__ out) {
    __shared__ float sa4[16][64], sm4[16][64];
    __shared__ float sa[64], sm[64], emb[64];
    int t = threadIdx.x;
    int ch = t & 63, part = t >> 6;
    float s = 0.f, mx = 0.f;
    for (int b = part; b < NB_MLP; b += 16) {
        s += pb_sum[b * 64 + ch];
        mx = fmaxf(mx, pb_max[b * 64 + ch]);
    }
    sa4[part][ch] = s; sm4[part][ch] = mx;
    __syncthreads();
    if (t < 64) {
        float ss = 0.f, mm = 0.f;
        #pragma unroll
        for (int q = 0; q < 16; ++q) {
            ss += sa4[q][t];
            mm = fmaxf(mm, sm4[q][t]);
        }
        sa[t] = ss; sm[t] = mm;
    }
    __syncthreads();
    if (t < 64) {
        if (t < 32) {
            emb[t] = (sa[2 * t] + sa[2 * t + 1]) * (0.5f / (float)N_NODES);
        } else {
            int i = t - 32;
            emb[t] = fmaxf(sm[2 * i], sm[2 * i + 1]);
        }
    }
    __syncthreads();
    if (t < 64) {
        float acc = bl[t];
        for (int k = 0; k < 64; ++k) acc = fmaf(emb[k], Wl[k * 64 + t], acc);
        out[t] = acc;
    }
}

extern "C" void kernel_launch(void* const* d_in, const int* in_sizes, int n_in,
                              void* d_out, int out_size, void* d_ws, size_t ws_size,
                              hipStream_t stream) {
    const float* x     = (const float*)d_in[0];
    const float* eattr = (const float*)d_in[1];
    const int*   ei    = (const int*)d_in[2];
    const float* Wn    = (const float*)d_in[3];
    const float* bn    = (const float*)d_in[4];
    const float* We    = (const float*)d_in[5];
    const float* be    = (const float*)d_in[6];
    const float* t     = (const float*)d_in[7];
    const float* W1    = (const float*)d_in[8];
    const float* b1    = (const float*)d_in[9];
    const float* lg    = (const float*)d_in[10];
    const float* lb    = (const float*)d_in[11];
    const float* W2    = (const float*)d_in[12];
    const float* b2    = (const float*)d_in[13];
    const float* ng    = (const float*)d_in[14];
    const float* nb    = (const float*)d_in[15];
    const float* Wl    = (const float*)d_in[16];
    const float* bl    = (const float*)d_in[17];
    float* out = (float*)d_out;

    char* p = (char*)d_ws;
    unsigned short* hb = (unsigned short*)p; p += (size_t)N_NODES * 64 * 2;
    unsigned short* zA = (unsigned short*)p; p += (size_t)N_NODES * 64 * 2;
    unsigned short* zB = (unsigned short*)p; p += (size_t)N_NODES * 64 * 2;
    unsigned int* s_pack = (unsigned int*)p; p += (size_t)N_NODES * CAP * 4;
    int* cnt    = (int*)p;  p += (size_t)N_NODES * 4;
    int* gcnt   = (int*)p;  p += (size_t)256 * 4;
    uint2* coarse = (uint2*)p; p += (size_t)NBK * BKCAP * 8;
    float* pb_sum = (float*)p; p += (size_t)NB_MLP * 64 * 4;
    float* pb_max = (float*)p; p += (size_t)NB_MLP * 64 * 4;
    unsigned short* w1p = (unsigned short*)p; p += (size_t)3 * 8192 * 2;
    unsigned short* w2p = (unsigned short*)p; p += (size_t)3 * 8192 * 2;

    hipMemsetAsync(gcnt, 0, (size_t)NBK * sizeof(int), stream);

    k_front<<<NB1 + NB_ENC + NB_WPREP, 256, 0, stream>>>(
        x, Wn, bn, zA, W1, W2, w1p, w2p, ei, eattr, gcnt, coarse);
    k_bin2<<<NBK * 2, 256, 0, stream>>>(gcnt, coarse, cnt, s_pack);

    // layer 0: z = zA -> zB
    k_layer<<<NB_MLP, 256, 0, stream>>>(zA, zB, hb, cnt, s_pack, We, be, t, 0,
                                        w1p, w2p, b1, lg, lb, b2,
                                        ng + 64, nb + 64, 0, pb_sum, pb_max);
    // layer 1: z = zB -> zA
    k_layer<<<NB_MLP, 256, 0, stream>>>(zB, zA, hb, cnt, s_pack, We, be, t, 1,
                                        w1p + 8192, w2p + 8192,
                                        b1 + 128, lg + 128, lb + 128, b2 + 64,
                                        ng + 128, nb + 128, 1, pb_sum, pb_max);
    // layer 2: z = zA (pooled, no z out)
    k_layer<<<NB_MLP, 256, 0, stream>>>(zA, zB, hb, cnt, s_pack, We, be, t, 2,
                                        w1p + 2 * 8192, w2p + 2 * 8192,
                                        b1 + 2 * 128, lg + 2 * 128, lb + 2 * 128, b2 + 2 * 64,
                                        ng, nb, 2, pb_sum, pb_max);

    k_head<<<1, 1024, 0, stream>>>(pb_sum, pb_max, Wl, bl, out);
}

// Round 8
// 358.220 us; speedup vs baseline: 1.3284x; 1.3284x over previous
//
#include <hip/hip_runtime.h>
#include <math.h>

#define N_NODES 50000
#define N_EDGES 1000000
#define HID 64
#define CAP 64                          // slots per node (P(deg>=64) ~ 1e-10 for this input)
#define N_TILES (N_NODES / 16)          // 3125
#define NB_MLP 782                      // mlp blocks: 782*4 waves = 3128 >= 3125 tiles, 1 tile/wave
#define VB_S 72                         // vb row stride (ushorts)
#define UB_S 136                        // ub row stride (ushorts)
#define NB_ENC ((N_NODES + 3) / 4)      // 12500
#define NB_WPREP ((3 * 8192 + 255) / 256) // 96
#define NBK 196                         // coarse buckets = dst>>8 (50000>>8 = 195)
#define BKCAP 6144                      // bucket capacity (mean 5120, +14 sigma)
#define EPB 4096                        // edges per pass-1 block
#define NB1 ((N_EDGES + EPB - 1) / EPB) // 245
static_assert(N_NODES % 16 == 0, "tile math");
static_assert(N_NODES <= 65536, "src must fit in 16 bits");

typedef __attribute__((ext_vector_type(8))) short short8;   // 8 bf16 = 4 VGPRs
typedef __attribute__((ext_vector_type(4))) float f32x4;

__device__ __forceinline__ unsigned short f2bf(float x) {   // RNE float->bf16
    unsigned u = __float_as_uint(x);
    u += 0x7FFFu + ((u >> 16) & 1u);
    return (unsigned short)(u >> 16);
}
__device__ __forceinline__ float bfbits_hi(unsigned pk) {
    return __uint_as_float(pk & 0xFFFF0000u);
}
__device__ __forceinline__ float bf2f(unsigned short v) {
    return __uint_as_float(((unsigned)v) << 16);
}
__device__ __forceinline__ unsigned addpk(unsigned a, unsigned b) {
    float lo = __uint_as_float(a << 16) + __uint_as_float(b << 16);
    float hi = __uint_as_float(a & 0xFFFF0000u) + __uint_as_float(b & 0xFFFF0000u);
    return (unsigned)f2bf(lo) | ((unsigned)f2bf(hi) << 16);
}

// ---------------- fused front: bin1 coarse scatter | node encoder | weight prep ----------------
__global__ __launch_bounds__(256) void k_front(
    const float* __restrict__ x, const float* __restrict__ Wn,
    const float* __restrict__ bn, unsigned short* __restrict__ zb,
    const float* __restrict__ W1, const float* __restrict__ W2,
    unsigned short* __restrict__ w1p, unsigned short* __restrict__ w2p,
    const int* __restrict__ ei, const float* __restrict__ eattr,
    int* __restrict__ gcnt, uint2* __restrict__ coarse) {
    __shared__ unsigned pk_l[EPB];          // 16 KB
    __shared__ unsigned short dst_l[EPB];   // 8 KB
    __shared__ unsigned spk[EPB];           // 16 KB (bucket-sorted)
    __shared__ unsigned short sdst[EPB];    // 8 KB
    __shared__ int hist[NBK], loc[NBK], gbase[NBK], cur[NBK];
    __shared__ int inc[256];
    int b = blockIdx.x;
    if (b < NB1) {
        // pass 1: LDS-binned coarse scatter (dst>>8 buckets)
        int tid = threadIdx.x;
        int e0 = b * EPB;
        int nel = N_EDGES - e0; if (nel > EPB) nel = EPB;
        for (int q = tid; q < NBK; q += 256) { hist[q] = 0; cur[q] = 0; }
        __syncthreads();
        for (int j = tid; j < nel; j += 256) {
            int i = e0 + j;
            int d = ei[N_EDGES + i];
            unsigned pk = ((unsigned)f2bf(eattr[i]) << 16) | (unsigned)(ei[i] & 0xFFFF);
            pk_l[j] = pk; dst_l[j] = (unsigned short)d;
            atomicAdd(&hist[d >> 8], 1);
        }
        __syncthreads();
        int v = (tid < NBK) ? hist[tid] : 0;
        inc[tid] = v;
        __syncthreads();
        #pragma unroll
        for (int dd = 1; dd < 256; dd <<= 1) {
            int t2 = (tid >= dd) ? inc[tid - dd] : 0;
            __syncthreads();
            inc[tid] += t2;
            __syncthreads();
        }
        if (tid < NBK) {
            loc[tid] = inc[tid] - v;                     // exclusive local offset
            gbase[tid] = atomicAdd(&gcnt[tid], v);       // reserve bucket space
        }
        __syncthreads();
        // local counting sort by bucket
        for (int j = tid; j < nel; j += 256) {
            int bkt = dst_l[j] >> 8;
            int r = atomicAdd(&cur[bkt], 1);
            int pos = loc[bkt] + r;
            spk[pos] = pk_l[j]; sdst[pos] = dst_l[j];
        }
        __syncthreads();
        // write out: consecutive j within a bucket run -> consecutive global addresses
        for (int j = tid; j < nel; j += 256) {
            int d = sdst[j];
            int bkt = d >> 8;
            int off = gbase[bkt] + (j - loc[bkt]);
            if (off < BKCAP) coarse[(size_t)bkt * BKCAP + off] = make_uint2(spk[j], (unsigned)d);
        }
    } else if (b < NB1 + NB_ENC) {
        // node encoder: zb = bf16(x @ W_node + b_node)
        int n = (b - NB1) * 4 + (threadIdx.x >> 6);
        int c = threadIdx.x & 63;
        if (n >= N_NODES) return;
        float acc = bn[c];
        const float* xr = x + n * 16;
        #pragma unroll
        for (int k = 0; k < 16; ++k) acc = fmaf(xr[k], Wn[k * 64 + c], acc);
        zb[n * 64 + c] = f2bf(acc);
    } else {
        // weight prep: pack W1/W2 (3 layers) into bf16 fragment order
        int i = (b - NB1 - NB_ENC) * 256 + threadIdx.x;
        if (i >= 3 * 8192) return;
        int L = i >> 13, r = i & 8191;
        int j = r & 7, lane = (r >> 3) & 63;
        int quad = lane >> 4, col = lane & 15;
        {
            int st = r >> 9;                 // s=st>>3 (2), t=st&7 (8)
            int s = st >> 3, t = st & 7;
            w1p[i] = f2bf(W1[L * 8192 + (s * 32 + quad * 8 + j) * 128 + t * 16 + col]);
        }
        {
            int ft = r >> 9;                 // s=ft>>2 (4), t=ft&3 (4)
            int s = ft >> 2, t = ft & 3;
            w2p[i] = f2bf(W2[L * 8192 + (s * 32 + quad * 8 + j) * 64 + t * 16 + col]);
        }
    }
}

// ---------------- pass 2: per-half-bucket fine CSR in LDS -> CAP-slotted s_pack, src-sorted ----
// 392 blocks: block handles bucket b>>1, node-halves (b&1)*128..+127.
// After the per-node scatter, each node's segment is insertion-sorted by src so that
// k_agg's waves walk zb in ascending-src order (temporal L2/L3 phasing across the grid).
__global__ __launch_bounds__(256) void k_bin2(
    const int* __restrict__ gcnt, const uint2* __restrict__ coarse,
    int* __restrict__ cnt, unsigned int* __restrict__ s_pack) {
    __shared__ unsigned epk[BKCAP];          // 24 KB
    __shared__ unsigned char eln[BKCAP];     // 6 KB
    __shared__ unsigned spk[BKCAP];          // 24 KB (node-sorted, in-range only)
    __shared__ unsigned char sln[BKCAP];     // 6 KB
    __shared__ int hist[128], loc[128], cur[128], inc2[128];
    int tid = threadIdx.x;
    int bkt = blockIdx.x >> 1;
    int hsel = blockIdx.x & 1;               // ln half select (ln>>7)
    int m = gcnt[bkt]; if (m > BKCAP) m = BKCAP;
    if (tid < 128) { hist[tid] = 0; cur[tid] = 0; }
    __syncthreads();
    for (int j = tid; j < m; j += 256) {
        uint2 e = coarse[(size_t)bkt * BKCAP + j];
        epk[j] = e.x;
        int ln = (int)(e.y & 255u);
        eln[j] = (unsigned char)ln;
        if ((ln >> 7) == hsel) atomicAdd(&hist[ln & 127], 1);
    }
    __syncthreads();
    int v = (tid < 128) ? hist[tid] : 0;
    if (tid < 128) inc2[tid] = v;
    __syncthreads();
    #pragma unroll
    for (int dd = 1; dd < 128; dd <<= 1) {
        int t2 = (tid >= dd && tid < 128) ? inc2[tid - dd] : 0;
        __syncthreads();
        if (tid < 128) inc2[tid] += t2;
        __syncthreads();
    }
    if (tid < 128) {
        loc[tid] = inc2[tid] - v;            // exclusive
        int node = bkt * 256 + hsel * 128 + tid;
        if (node < N_NODES) cnt[node] = v;
    }
    __syncthreads();
    int mh = inc2[127];                      // in-range edge count
    for (int j = tid; j < m; j += 256) {
        int ln = eln[j];
        if ((ln >> 7) == hsel) {
            int r = atomicAdd(&cur[ln & 127], 1);
            int pos = loc[ln & 127] + r;
            spk[pos] = epk[j]; sln[pos] = (unsigned char)ln;
        }
    }
    __syncthreads();
    // per-node insertion sort by src (low 16 bits); sln is constant within a segment
    if (tid < 128 && v > 1) {
        int b0 = loc[tid];
        for (int a = b0 + 1; a < b0 + v; ++a) {
            unsigned key = spk[a];
            int kb = (int)(key & 0xFFFFu);
            int c = a - 1;
            while (c >= b0 && (int)(spk[c] & 0xFFFFu) > kb) {
                spk[c + 1] = spk[c];
                --c;
            }
            spk[c + 1] = key;
        }
    }
    __syncthreads();
    for (int j = tid; j < mh; j += 256) {
        int ln = sln[j];
        int k = j - loc[ln & 127];
        if (k < CAP) s_pack[(size_t)(bkt * 256 + ln) * CAP + k] = spk[j];
    }
}

// ---------------- softmax aggregation: one wave/node, 2 edges/gather, 16-edge ILP ----------------
// lanes 0-31: even edge, lanes 32-63: odd edge; each lane owns channels {2c2, 2c2+1}
__global__ __launch_bounds__(256) void k_agg(
    const unsigned short* __restrict__ zb, const int* __restrict__ cnt,
    const unsigned int* __restrict__ s_pack,
    const float* __restrict__ We, const float* __restrict__ be,
    const float* __restrict__ t, int layer, unsigned short* __restrict__ aggb) {
    int wid = (blockIdx.x * blockDim.x + threadIdx.x) >> 6;
    int lane = threadIdx.x & 63;
    if (wid >= N_NODES) return;
    int deg = cnt[wid];
    deg = (deg < CAP) ? deg : CAP;
    int beg = wid * CAP, end = beg + deg;
    int half = lane >> 5;          // 0: even edge of pair, 1: odd edge
    int c2 = lane & 31;            // uint index in row; channels 2c2, 2c2+1
    float we0 = We[2 * c2], we1 = We[2 * c2 + 1];
    float bv0 = be[2 * c2], bv1 = be[2 * c2 + 1];
    float tl = t[layer];
    const unsigned* zbu = (const unsigned*)zb;
    float s0 = 0.f, s1 = 0.f, n0 = 0.f, n1 = 0.f;
    int i = beg;
    // 16-edge iter: 8 independent gathers in flight (latency hiding)
    for (; i + 15 < end; i += 16) {
        unsigned pk[8];
        #pragma unroll
        for (int j = 0; j < 8; ++j) {
            unsigned pa = s_pack[i + 2 * j];
            unsigned pb = s_pack[i + 2 * j + 1];
            pk[j] = half ? pb : pa;
        }
        unsigned zu[8];
        #pragma unroll
        for (int j = 0; j < 8; ++j) zu[j] = zbu[(pk[j] & 0xFFFFu) * 32 + c2];
        #pragma unroll
        for (int j = 0; j < 8; ++j) {
            float ea = bfbits_hi(pk[j]);
            float z0 = __uint_as_float(zu[j] << 16);
            float z1 = __uint_as_float(zu[j] & 0xFFFF0000u);
            float m0 = fmaxf(z0 + fmaf(ea, we0, bv0), 0.f) + 1e-7f;
            float m1 = fmaxf(z1 + fmaf(ea, we1, bv1), 0.f) + 1e-7f;
            float p0 = __expf(m0 * tl), p1 = __expf(m1 * tl);
            s0 += p0; n0 = fmaf(p0, m0, n0);
            s1 += p1; n1 = fmaf(p1, m1, n1);
        }
    }
    for (; i + 7 < end; i += 8) {
        unsigned pk[4];
        #pragma unroll
        for (int j = 0; j < 4; ++j) {
            unsigned pa = s_pack[i + 2 * j];
            unsigned pb = s_pack[i + 2 * j + 1];
            pk[j] = half ? pb : pa;
        }
        unsigned zu[4];
        #pragma unroll
        for (int j = 0; j < 4; ++j) zu[j] = zbu[(pk[j] & 0xFFFFu) * 32 + c2];
        #pragma unroll
        for (int j = 0; j < 4; ++j) {
            float ea = bfbits_hi(pk[j]);
            float z0 = __uint_as_float(zu[j] << 16);
            float z1 = __uint_as_float(zu[j] & 0xFFFF0000u);
            float m0 = fmaxf(z0 + fmaf(ea, we0, bv0), 0.f) + 1e-7f;
            float m1 = fmaxf(z1 + fmaf(ea, we1, bv1), 0.f) + 1e-7f;
            float p0 = __expf(m0 * tl), p1 = __expf(m1 * tl);
            s0 += p0; n0 = fmaf(p0, m0, n0);
            s1 += p1; n1 = fmaf(p1, m1, n1);
        }
    }
    for (; i + 1 < end; i += 2) {
        unsigned pa = s_pack[i], pb = s_pack[i + 1];
        unsigned pk = half ? pb : pa;
        unsigned zu = zbu[(pk & 0xFFFFu) * 32 + c2];
        float ea = bfbits_hi(pk);
        float z0 = __uint_as_float(zu << 16);
        float z1 = __uint_as_float(zu & 0xFFFF0000u);
        float m0 = fmaxf(z0 + fmaf(ea, we0, bv0), 0.f) + 1e-7f;
        float m1 = fmaxf(z1 + fmaf(ea, we1, bv1), 0.f) + 1e-7f;
        float p0 = __expf(m0 * tl), p1 = __expf(m1 * tl);
        s0 += p0; n0 = fmaf(p0, m0, n0);
        s1 += p1; n1 = fmaf(p1, m1, n1);
    }
    if (i < end) {                 // single leftover edge: lo half only
        unsigned pk = s_pack[i];
        unsigned zu = zbu[(pk & 0xFFFFu) * 32 + c2];
        float ea = bfbits_hi(pk);
        float z0 = __uint_as_float(zu << 16);
        float z1 = __uint_as_float(zu & 0xFFFF0000u);
        float m0 = fmaxf(z0 + fmaf(ea, we0, bv0), 0.f) + 1e-7f;
        float m1 = fmaxf(z1 + fmaf(ea, we1, bv1), 0.f) + 1e-7f;
        float p0 = __expf(m0 * tl), p1 = __expf(m1 * tl);
        if (half == 0) {
            s0 += p0; n0 = fmaf(p0, m0, n0);
            s1 += p1; n1 = fmaf(p1, m1, n1);
        }
    }
    // combine even/odd halves
    s0 += __shfl_xor(s0, 32, 64); n0 += __shfl_xor(n0, 32, 64);
    s1 += __shfl_xor(s1, 32, 64); n1 += __shfl_xor(n1, 32, 64);
    if (half == 0) {
        unsigned r = (unsigned)f2bf(n0 / (s0 + 1e-16f)) |
                     ((unsigned)f2bf(n1 / (s1 + 1e-16f)) << 16);
        ((unsigned*)aggb)[wid * 32 + c2] = r;
    }
}

// ---------------- MFMA MLP: block-shared weights in LDS, coalesced epilogue ----------------
__global__ __launch_bounds__(256) void k_mlp(
    const unsigned short* __restrict__ aggb, unsigned short* __restrict__ zb,
    unsigned short* __restrict__ hb,
    const unsigned short* __restrict__ w1p, const unsigned short* __restrict__ w2p,
    const float* __restrict__ b1,
    const float* __restrict__ g1, const float* __restrict__ be1,
    const float* __restrict__ b2,
    const float* __restrict__ ng, const float* __restrict__ nb, int mode,
    float* __restrict__ pb_sum, float* __restrict__ pb_max) {
    __shared__ unsigned short w1s[8192];
    __shared__ unsigned short w2s[8192];
    __shared__ unsigned short vbuf[4][16 * VB_S];
    __shared__ unsigned short ubuf[4][16 * UB_S];
    __shared__ float lssum[4][4][16], lsmax[4][4][16];
    int lane = threadIdx.x & 63;
    int wave = threadIdx.x >> 6;
    int col = lane & 15, quad = lane >> 4;
    unsigned short* vb = vbuf[wave];
    unsigned short* ub = ubuf[wave];

    {
        const uint4* s1 = (const uint4*)w1p;
        const uint4* s2 = (const uint4*)w2p;
        uint4* d1 = (uint4*)w1s;
        uint4* d2 = (uint4*)w2s;
        #pragma unroll
        for (int i = 0; i < 4; ++i) {
            d1[threadIdx.x + i * 256] = s1[threadIdx.x + i * 256];
            d2[threadIdx.x + i * 256] = s2[threadIdx.x + i * 256];
        }
    }
    __syncthreads();

    float b1f[8], g1f[8], e1f[8];
    #pragma unroll
    for (int t = 0; t < 8; ++t) {
        int ch = t * 16 + col;
        b1f[t] = b1[ch]; g1f[t] = g1[ch]; e1f[t] = be1[ch];
    }
    float b2f_[4], ngf[4], nbf[4];
    #pragma unroll
    for (int t = 0; t < 4; ++t) {
        b2f_[t] = b2[t * 16 + col];
        ngf[t] = ng[t * 16 + col];
        nbf[t] = nb[t * 16 + col];
    }

    float psum[4] = {0.f, 0.f, 0.f, 0.f};
    float pmax[4] = {0.f, 0.f, 0.f, 0.f};
    int nd = lane >> 2;
    int cg = (lane & 3) * 16;

    for (int tile = blockIdx.x * 4 + wave; tile < N_TILES; tile += NB_MLP * 4) {
        int n0 = tile * 16;
        const uint4* ap = (const uint4*)(aggb + (size_t)(n0 + nd) * 64 + cg);
        const uint4* zp = (const uint4*)(zb + (size_t)(n0 + nd) * 64 + cg);
        uint4 a0 = ap[0], a1 = ap[1], z0 = zp[0], z1 = zp[1];
        uint4 r0, r1;
        r0.x = addpk(a0.x, z0.x); r0.y = addpk(a0.y, z0.y);
        r0.z = addpk(a0.z, z0.z); r0.w = addpk(a0.w, z0.w);
        r1.x = addpk(a1.x, z1.x); r1.y = addpk(a1.y, z1.y);
        r1.z = addpk(a1.z, z1.z); r1.w = addpk(a1.w, z1.w);
        uint4* vdst = (uint4*)&vb[nd * VB_S + cg];
        vdst[0] = r0;
        vdst[1] = r1;

        short8 af0 = *(const short8*)&vb[col * VB_S + quad * 8];
        short8 af1 = *(const short8*)&vb[col * VB_S + 32 + quad * 8];

        uint4 h0, h1;
        if (mode >= 1) {
            const uint4* hp = (const uint4*)(hb + (size_t)(n0 + nd) * 64 + cg);
            h0 = hp[0]; h1 = hp[1];
        }

        f32x4 au[8];
        #pragma unroll
        for (int t = 0; t < 8; ++t) {
            short8 w0 = *(const short8*)&w1s[((0 * 8 + t) * 64 + lane) * 8];
            short8 w1 = *(const short8*)&w1s[((1 * 8 + t) * 64 + lane) * 8];
            f32x4 c = {0.f, 0.f, 0.f, 0.f};
            c = __builtin_amdgcn_mfma_f32_16x16x32_bf16(af0, w0, c, 0, 0, 0);
            c = __builtin_amdgcn_mfma_f32_16x16x32_bf16(af1, w1, c, 0, 0, 0);
            au[t] = c;
        }
        #pragma unroll
        for (int r = 0; r < 4; ++r) {
            float sx = 0.f, sq = 0.f;
            #pragma unroll
            for (int t = 0; t < 8; ++t) {
                float v = au[t][r] + b1f[t];
                sx += v; sq += v * v;
            }
            #pragma unroll
            for (int mask = 1; mask < 16; mask <<= 1) {
                sx += __shfl_xor(sx, mask, 64);
                sq += __shfl_xor(sq, mask, 64);
            }
            float mu = sx * (1.f / 128.f);
            float var = sq * (1.f / 128.f) - mu * mu;
            float rs = rsqrtf(var + 1e-5f);
            int row = quad * 4 + r;
            #pragma unroll
            for (int t = 0; t < 8; ++t) {
                float v = au[t][r] + b1f[t];
                float y = fmaxf(fmaf((v - mu) * rs, g1f[t], e1f[t]), 0.f);
                ub[row * UB_S + t * 16 + col] = f2bf(y);
            }
        }
        f32x4 oc[4];
        #pragma unroll
        for (int t = 0; t < 4; ++t) oc[t] = (f32x4){0.f, 0.f, 0.f, 0.f};
        #pragma unroll
        for (int s = 0; s < 4; ++s) {
            short8 a = *(const short8*)&ub[col * UB_S + s * 32 + quad * 8];
            #pragma unroll
            for (int t = 0; t < 4; ++t) {
                short8 w = *(const short8*)&w2s[((s * 4 + t) * 64 + lane) * 8];
                oc[t] = __builtin_amdgcn_mfma_f32_16x16x32_bf16(a, w, oc[t], 0, 0, 0);
            }
        }
        if (mode >= 1) {
            uint4* hdst = (uint4*)&vb[nd * VB_S + cg];
            hdst[0] = h0;
            hdst[1] = h1;
        }
        #pragma unroll
        for (int r = 0; r < 4; ++r) {
            int row = quad * 4 + r;
            float val[4];
            #pragma unroll
            for (int t = 0; t < 4; ++t) {
                val[t] = oc[t][r] + b2f_[t];
                if (mode >= 1) val[t] += bf2f(vb[row * VB_S + t * 16 + col]);
            }
            float sx = 0.f, sq = 0.f;
            #pragma unroll
            for (int t = 0; t < 4; ++t) { sx += val[t]; sq += val[t] * val[t]; }
            #pragma unroll
            for (int mask = 1; mask < 16; mask <<= 1) {
                sx += __shfl_xor(sx, mask, 64);
                sq += __shfl_xor(sq, mask, 64);
            }
            float mu = sx * (1.f / 64.f);
            float var = sq * (1.f / 64.f) - mu * mu;
            float rs = rsqrtf(var + 1e-5f);
            #pragma unroll
            for (int t = 0; t < 4; ++t) {
                float y = fmaxf(fmaf((val[t] - mu) * rs, ngf[t], nbf[t]), 0.f);
                if (mode <= 1) {
                    vb[row * VB_S + t * 16 + col] = f2bf(val[t]);   // h
                    ub[row * UB_S + t * 16 + col] = f2bf(y);        // z
                } else {
                    psum[t] += y;
                    pmax[t] = fmaxf(pmax[t], y);
                }
            }
        }
        if (mode <= 1) {
            const uint4* hsrc = (const uint4*)&vb[nd * VB_S + cg];
            const uint4* zsrc = (const uint4*)&ub[nd * UB_S + cg];
            uint4* hdst = (uint4*)(hb + (size_t)(n0 + nd) * 64 + cg);
            uint4* zdst = (uint4*)(zb + (size_t)(n0 + nd) * 64 + cg);
            hdst[0] = hsrc[0]; hdst[1] = hsrc[1];
            zdst[0] = zsrc[0]; zdst[1] = zsrc[1];
        }
    }
    if (mode == 2) {
        #pragma unroll
        for (int t = 0; t < 4; ++t) {
            psum[t] += __shfl_xor(psum[t], 16, 64);
            psum[t] += __shfl_xor(psum[t], 32, 64);
            pmax[t] = fmaxf(pmax[t], __shfl_xor(pmax[t], 16, 64));
            pmax[t] = fmaxf(pmax[t], __shfl_xor(pmax[t], 32, 64));
        }
        if (quad == 0) {
            #pragma unroll
            for (int t = 0; t < 4; ++t) {
                lssum[wave][t][col] = psum[t];
                lsmax[wave][t][col] = pmax[t];
            }
        }
        __syncthreads();
        if (wave == 0) {
            int t = lane >> 4, c = lane & 15;
            float s = lssum[0][t][c] + lssum[1][t][c] + lssum[2][t][c] + lssum[3][t][c];
            float mx = fmaxf(fmaxf(lsmax[0][t][c], lsmax[1][t][c]),
                             fmaxf(lsmax[2][t][c], lsmax[3][t][c]));
            pb_sum[blockIdx.x * 64 + lane] = s;
            pb_max[blockIdx.x * 64 + lane] = mx;
        }
    }
}

// ---------------- head: full partial reduction + pooling + linear ----------------
__global__ __launch_bounds__(1024) void k_head(
    const float* __restrict__ pb_sum, const float* __restrict__ pb_max,
    const float* __restrict__ Wl, const float* __restrict__ bl, float* __restrict__ out) {
    __shared__ float sa4[16][64], sm4[16][64];
    __shared__ float sa[64], sm[64], emb[64];
    int t = threadIdx.x;
    int ch = t & 63, part = t >> 6;
    float s = 0.f, mx = 0.f;
    for (int b = part; b < NB_MLP; b += 16) {
        s += pb_sum[b * 64 + ch];
        mx = fmaxf(mx, pb_max[b * 64 + ch]);
    }
    sa4[part][ch] = s; sm4[part][ch] = mx;
    __syncthreads();
    if (t < 64) {
        float ss = 0.f, mm = 0.f;
        #pragma unroll
        for (int q = 0; q < 16; ++q) {
            ss += sa4[q][t];
            mm = fmaxf(mm, sm4[q][t]);
        }
        sa[t] = ss; sm[t] = mm;
    }
    __syncthreads();
    if (t < 64) {
        if (t < 32) {
            emb[t] = (sa[2 * t] + sa[2 * t + 1]) * (0.5f / (float)N_NODES);
        } else {
            int i = t - 32;
            emb[t] = fmaxf(sm[2 * i], sm[2 * i + 1]);
        }
    }
    __syncthreads();
    if (t < 64) {
        float acc = bl[t];
        for (int k = 0; k < 64; ++k) acc = fmaf(emb[k], Wl[k * 64 + t], acc);
        out[t] = acc;
    }
}

extern "C" void kernel_launch(void* const* d_in, const int* in_sizes, int n_in,
                              void* d_out, int out_size, void* d_ws, size_t ws_size,
                              hipStream_t stream) {
    const float* x     = (const float*)d_in[0];
    const float* eattr = (const float*)d_in[1];
    const int*   ei    = (const int*)d_in[2];
    const float* Wn    = (const float*)d_in[3];
    const float* bn    = (const float*)d_in[4];
    const float* We    = (const float*)d_in[5];
    const float* be    = (const float*)d_in[6];
    const float* t     = (const float*)d_in[7];
    const float* W1    = (const float*)d_in[8];
    const float* b1    = (const float*)d_in[9];
    const float* lg    = (const float*)d_in[10];
    const float* lb    = (const float*)d_in[11];
    const float* W2    = (const float*)d_in[12];
    const float* b2    = (const float*)d_in[13];
    const float* ng    = (const float*)d_in[14];
    const float* nb    = (const float*)d_in[15];
    const float* Wl    = (const float*)d_in[16];
    const float* bl    = (const float*)d_in[17];
    float* out = (float*)d_out;

    char* p = (char*)d_ws;
    unsigned short* hb = (unsigned short*)p; p += (size_t)N_NODES * 64 * 2;
    unsigned short* zb = (unsigned short*)p; p += (size_t)N_NODES * 64 * 2;
    unsigned short* aggb = (unsigned short*)p; p += (size_t)N_NODES * 64 * 2;
    unsigned int* s_pack = (unsigned int*)p; p += (size_t)N_NODES * CAP * 4;
    int* cnt    = (int*)p;  p += (size_t)N_NODES * 4;
    int* gcnt   = (int*)p;  p += (size_t)256 * 4;
    uint2* coarse = (uint2*)p; p += (size_t)NBK * BKCAP * 8;
    float* pb_sum = (float*)p; p += (size_t)NB_MLP * 64 * 4;
    float* pb_max = (float*)p; p += (size_t)NB_MLP * 64 * 4;
    unsigned short* w1p = (unsigned short*)p; p += (size_t)3 * 8192 * 2;
    unsigned short* w2p = (unsigned short*)p; p += (size_t)3 * 8192 * 2;

    hipMemsetAsync(gcnt, 0, (size_t)NBK * sizeof(int), stream);

    k_front<<<NB1 + NB_ENC + NB_WPREP, 256, 0, stream>>>(
        x, Wn, bn, zb, W1, W2, w1p, w2p, ei, eattr, gcnt, coarse);
    k_bin2<<<NBK * 2, 256, 0, stream>>>(gcnt, coarse, cnt, s_pack);

    // layer 0
    k_agg<<<(N_NODES + 3) / 4, 256, 0, stream>>>(zb, cnt, s_pack, We, be, t, 0, aggb);
    k_mlp<<<NB_MLP, 256, 0, stream>>>(aggb, zb, hb, w1p, w2p, b1, lg, lb, b2,
                                      ng + 64, nb + 64, 0, pb_sum, pb_max);
    // layer 1
    k_agg<<<(N_NODES + 3) / 4, 256, 0, stream>>>(zb, cnt, s_pack, We, be, t, 1, aggb);
    k_mlp<<<NB_MLP, 256, 0, stream>>>(aggb, zb, hb, w1p + 8192, w2p + 8192,
                                      b1 + 128, lg + 128, lb + 128, b2 + 64,
                                      ng + 128, nb + 128, 1, pb_sum, pb_max);
    // layer 2
    k_agg<<<(N_NODES + 3) / 4, 256, 0, stream>>>(zb, cnt, s_pack, We, be, t, 2, aggb);
    k_mlp<<<NB_MLP, 256, 0, stream>>>(aggb, zb, hb, w1p + 2 * 8192, w2p + 2 * 8192,
                                      b1 + 2 * 128, lg + 2 * 128, lb + 2 * 128, b2 + 2 * 64,
                                      ng, nb, 2, pb_sum, pb_max);

    k_head<<<1, 1024, 0, stream>>>(pb_sum, pb_max, Wl, bl, out);
}

// Round 9
// 350.139 us; speedup vs baseline: 1.3591x; 1.0231x over previous
//
#include <hip/hip_runtime.h>
#include <math.h>

#define N_NODES 50000
#define N_EDGES 1000000
#define HID 64
#define CAP 64                          // slots per node (P(deg>=64) ~ 1e-10 for this input)
#define N_TILES (N_NODES / 16)          // 3125
#define NB_MLP 782                      // mlp blocks: 782*4 waves = 3128 >= 3125 tiles, 1 tile/wave
#define NB_AGG 25000                    // agg blocks: 2 halves x 12500, XCD-pinned by b%8
#define VB_S 72                         // vb row stride (ushorts)
#define UB_S 136                        // ub row stride (ushorts)
#define NB_ENC ((N_NODES + 3) / 4)      // 12500
#define NB_WPREP ((3 * 8192 + 255) / 256) // 96
#define NBK 196                         // coarse buckets = dst>>8 (50000>>8 = 195)
#define BKCAP 6144                      // bucket capacity (mean 5120, +14 sigma)
#define EPB 4096                        // edges per pass-1 block
#define NB1 ((N_EDGES + EPB - 1) / EPB) // 245
static_assert(N_NODES % 16 == 0, "tile math");
static_assert(N_NODES <= 65536, "src must fit in 16 bits");

typedef __attribute__((ext_vector_type(8))) short short8;   // 8 bf16 = 4 VGPRs
typedef __attribute__((ext_vector_type(4))) float f32x4;

__device__ __forceinline__ unsigned short f2bf(float x) {   // RNE float->bf16
    unsigned u = __float_as_uint(x);
    u += 0x7FFFu + ((u >> 16) & 1u);
    return (unsigned short)(u >> 16);
}
__device__ __forceinline__ float bfbits_hi(unsigned pk) {
    return __uint_as_float(pk & 0xFFFF0000u);
}
__device__ __forceinline__ float bf2f(unsigned short v) {
    return __uint_as_float(((unsigned)v) << 16);
}
__device__ __forceinline__ unsigned addpk(unsigned a, unsigned b) {
    float lo = __uint_as_float(a << 16) + __uint_as_float(b << 16);
    float hi = __uint_as_float(a & 0xFFFF0000u) + __uint_as_float(b & 0xFFFF0000u);
    return (unsigned)f2bf(lo) | ((unsigned)f2bf(hi) << 16);
}

// ---------------- fused front: bin1 coarse scatter | node encoder | weight prep ----------------
__global__ __launch_bounds__(256) void k_front(
    const float* __restrict__ x, const float* __restrict__ Wn,
    const float* __restrict__ bn,
    unsigned short* __restrict__ zlo, unsigned short* __restrict__ zhi,
    const float* __restrict__ W1, const float* __restrict__ W2,
    unsigned short* __restrict__ w1p, unsigned short* __restrict__ w2p,
    const int* __restrict__ ei, const float* __restrict__ eattr,
    int* __restrict__ gcnt, uint2* __restrict__ coarse) {
    __shared__ unsigned pk_l[EPB];          // 16 KB
    __shared__ unsigned short dst_l[EPB];   // 8 KB
    __shared__ unsigned spk[EPB];           // 16 KB (bucket-sorted)
    __shared__ unsigned short sdst[EPB];    // 8 KB
    __shared__ int hist[NBK], loc[NBK], gbase[NBK], cur[NBK];
    __shared__ int inc[256];
    int b = blockIdx.x;
    if (b < NB1) {
        // pass 1: LDS-binned coarse scatter (dst>>8 buckets)
        int tid = threadIdx.x;
        int e0 = b * EPB;
        int nel = N_EDGES - e0; if (nel > EPB) nel = EPB;
        for (int q = tid; q < NBK; q += 256) { hist[q] = 0; cur[q] = 0; }
        __syncthreads();
        for (int j = tid; j < nel; j += 256) {
            int i = e0 + j;
            int d = ei[N_EDGES + i];
            unsigned pk = ((unsigned)f2bf(eattr[i]) << 16) | (unsigned)(ei[i] & 0xFFFF);
            pk_l[j] = pk; dst_l[j] = (unsigned short)d;
            atomicAdd(&hist[d >> 8], 1);
        }
        __syncthreads();
        int v = (tid < NBK) ? hist[tid] : 0;
        inc[tid] = v;
        __syncthreads();
        #pragma unroll
        for (int dd = 1; dd < 256; dd <<= 1) {
            int t2 = (tid >= dd) ? inc[tid - dd] : 0;
            __syncthreads();
            inc[tid] += t2;
            __syncthreads();
        }
        if (tid < NBK) {
            loc[tid] = inc[tid] - v;                     // exclusive local offset
            gbase[tid] = atomicAdd(&gcnt[tid], v);       // reserve bucket space
        }
        __syncthreads();
        // local counting sort by bucket
        for (int j = tid; j < nel; j += 256) {
            int bkt = dst_l[j] >> 8;
            int r = atomicAdd(&cur[bkt], 1);
            int pos = loc[bkt] + r;
            spk[pos] = pk_l[j]; sdst[pos] = dst_l[j];
        }
        __syncthreads();
        // write out: consecutive j within a bucket run -> consecutive global addresses
        for (int j = tid; j < nel; j += 256) {
            int d = sdst[j];
            int bkt = d >> 8;
            int off = gbase[bkt] + (j - loc[bkt]);
            if (off < BKCAP) coarse[(size_t)bkt * BKCAP + off] = make_uint2(spk[j], (unsigned)d);
        }
    } else if (b < NB1 + NB_ENC) {
        // node encoder: z = bf16(x @ W_node + b_node), split into lo/hi channel tables
        int n = (b - NB1) * 4 + (threadIdx.x >> 6);
        int c = threadIdx.x & 63;
        if (n >= N_NODES) return;
        float acc = bn[c];
        const float* xr = x + n * 16;
        #pragma unroll
        for (int k = 0; k < 16; ++k) acc = fmaf(xr[k], Wn[k * 64 + c], acc);
        if (c < 32) zlo[n * 32 + c] = f2bf(acc);
        else        zhi[n * 32 + (c - 32)] = f2bf(acc);
    } else {
        // weight prep: pack W1/W2 (3 layers) into bf16 fragment order
        int i = (b - NB1 - NB_ENC) * 256 + threadIdx.x;
        if (i >= 3 * 8192) return;
        int L = i >> 13, r = i & 8191;
        int j = r & 7, lane = (r >> 3) & 63;
        int quad = lane >> 4, col = lane & 15;
        {
            int st = r >> 9;                 // s=st>>3 (2), t=st&7 (8)
            int s = st >> 3, t = st & 7;
            w1p[i] = f2bf(W1[L * 8192 + (s * 32 + quad * 8 + j) * 128 + t * 16 + col]);
        }
        {
            int ft = r >> 9;                 // s=ft>>2 (4), t=ft&3 (4)
            int s = ft >> 2, t = ft & 3;
            w2p[i] = f2bf(W2[L * 8192 + (s * 32 + quad * 8 + j) * 64 + t * 16 + col]);
        }
    }
}

// ---------------- pass 2: per-half-bucket fine CSR built in LDS -> CAP-slotted s_pack --------
// 392 blocks: block handles bucket b>>1, node-halves (b&1)*128..+127
__global__ __launch_bounds__(256) void k_bin2(
    const int* __restrict__ gcnt, const uint2* __restrict__ coarse,
    int* __restrict__ cnt, unsigned int* __restrict__ s_pack) {
    __shared__ unsigned epk[BKCAP];          // 24 KB
    __shared__ unsigned char eln[BKCAP];     // 6 KB
    __shared__ unsigned spk[BKCAP];          // 24 KB (node-sorted, in-range only)
    __shared__ unsigned char sln[BKCAP];     // 6 KB
    __shared__ int hist[128], loc[128], cur[128], inc2[128];
    int tid = threadIdx.x;
    int bkt = blockIdx.x >> 1;
    int hsel = blockIdx.x & 1;               // ln half select (ln>>7)
    int m = gcnt[bkt]; if (m > BKCAP) m = BKCAP;
    if (tid < 128) { hist[tid] = 0; cur[tid] = 0; }
    __syncthreads();
    for (int j = tid; j < m; j += 256) {
        uint2 e = coarse[(size_t)bkt * BKCAP + j];
        epk[j] = e.x;
        int ln = (int)(e.y & 255u);
        eln[j] = (unsigned char)ln;
        if ((ln >> 7) == hsel) atomicAdd(&hist[ln & 127], 1);
    }
    __syncthreads();
    int v = (tid < 128) ? hist[tid] : 0;
    if (tid < 128) inc2[tid] = v;
    __syncthreads();
    #pragma unroll
    for (int dd = 1; dd < 128; dd <<= 1) {
        int t2 = (tid >= dd && tid < 128) ? inc2[tid - dd] : 0;
        __syncthreads();
        if (tid < 128) inc2[tid] += t2;
        __syncthreads();
    }
    if (tid < 128) {
        loc[tid] = inc2[tid] - v;            // exclusive
        int node = bkt * 256 + hsel * 128 + tid;
        if (node < N_NODES) cnt[node] = v;
    }
    __syncthreads();
    int mh = inc2[127];                      // in-range edge count
    for (int j = tid; j < m; j += 256) {
        int ln = eln[j];
        if ((ln >> 7) == hsel) {
            int r = atomicAdd(&cur[ln & 127], 1);
            int pos = loc[ln & 127] + r;
            spk[pos] = epk[j]; sln[pos] = (unsigned char)ln;
        }
    }
    __syncthreads();
    for (int j = tid; j < mh; j += 256) {
        int ln = sln[j];
        int k = j - loc[ln & 127];
        if (k < CAP) s_pack[(size_t)(bkt * 256 + ln) * CAP + k] = spk[j];
    }
}

// ---------------- softmax aggregation: one wave per (node, channel-half) ----------------
// XCD-pinned: b%8<4 -> lo half (zlo, 3.2MB, fits 4MB per-XCD L2), b%8>=4 -> hi half.
// Within a wave: e4=lane>>4 picks 1 of 4 edges, c4=lane&15 picks the uint (2 ch) of the 64B half-row.
__global__ __launch_bounds__(256) void k_agg(
    const unsigned short* __restrict__ zlo, const unsigned short* __restrict__ zhi,
    const int* __restrict__ cnt, const unsigned int* __restrict__ s_pack,
    const float* __restrict__ We, const float* __restrict__ be,
    const float* __restrict__ t, int layer, unsigned int* __restrict__ aggb) {
    int b = blockIdx.x;
    int r8 = b & 7;
    int h = (r8 >= 4) ? 1 : 0;
    int idx = (b >> 3) * 4 + (r8 & 3);       // 0..12499 (bijective per half)
    int wave = threadIdx.x >> 6;
    int lane = threadIdx.x & 63;
    int node = idx * 4 + wave;               // < 50000 always
    int e4 = lane >> 4;                      // edge within quad group
    int c4 = lane & 15;                      // uint index within 64B half-row
    const unsigned* zt = (const unsigned*)(h ? zhi : zlo);
    int ch = h * 32 + 2 * c4;
    float we0 = We[ch], we1 = We[ch + 1];
    float bv0 = be[ch], bv1 = be[ch + 1];
    float tl = t[layer];
    int deg = cnt[node];
    deg = (deg < CAP) ? deg : CAP;
    int beg = node * CAP, end = beg + deg;
    float s0 = 0.f, s1 = 0.f, n0 = 0.f, n1 = 0.f;
    int i = beg;
    // 16 edges/iter: 4 uniform pk loads + 4 gathers in flight
    for (; i + 15 < end; i += 16) {
        uint4 pv[4];
        #pragma unroll
        for (int q = 0; q < 4; ++q) pv[q] = *(const uint4*)&s_pack[i + 4 * q];
        unsigned pk[4];
        #pragma unroll
        for (int q = 0; q < 4; ++q)
            pk[q] = (e4 & 2) ? ((e4 & 1) ? pv[q].w : pv[q].z) : ((e4 & 1) ? pv[q].y : pv[q].x);
        unsigned zu[4];
        #pragma unroll
        for (int q = 0; q < 4; ++q) zu[q] = zt[(pk[q] & 0xFFFFu) * 16 + c4];
        #pragma unroll
        for (int q = 0; q < 4; ++q) {
            float ea = bfbits_hi(pk[q]);
            float z0 = __uint_as_float(zu[q] << 16);
            float z1 = __uint_as_float(zu[q] & 0xFFFF0000u);
            float m0 = fmaxf(z0 + fmaf(ea, we0, bv0), 0.f) + 1e-7f;
            float m1 = fmaxf(z1 + fmaf(ea, we1, bv1), 0.f) + 1e-7f;
            float p0 = __expf(m0 * tl), p1 = __expf(m1 * tl);
            s0 += p0; n0 = fmaf(p0, m0, n0);
            s1 += p1; n1 = fmaf(p1, m1, n1);
        }
    }
    for (; i + 3 < end; i += 4) {
        uint4 pv = *(const uint4*)&s_pack[i];
        unsigned pk = (e4 & 2) ? ((e4 & 1) ? pv.w : pv.z) : ((e4 & 1) ? pv.y : pv.x);
        unsigned zu = zt[(pk & 0xFFFFu) * 16 + c4];
        float ea = bfbits_hi(pk);
        float z0 = __uint_as_float(zu << 16);
        float z1 = __uint_as_float(zu & 0xFFFF0000u);
        float m0 = fmaxf(z0 + fmaf(ea, we0, bv0), 0.f) + 1e-7f;
        float m1 = fmaxf(z1 + fmaf(ea, we1, bv1), 0.f) + 1e-7f;
        float p0 = __expf(m0 * tl), p1 = __expf(m1 * tl);
        s0 += p0; n0 = fmaf(p0, m0, n0);
        s1 += p1; n1 = fmaf(p1, m1, n1);
    }
    if (i < end) {                           // 1..3 leftover: clamped + masked
        int idx2 = i + e4;
        bool ok = idx2 < end;
        if (!ok) idx2 = end - 1;             // deg>=1 here, stays in node region
        unsigned pk = s_pack[idx2];
        unsigned zu = zt[(pk & 0xFFFFu) * 16 + c4];
        float ea = bfbits_hi(pk);
        float z0 = __uint_as_float(zu << 16);
        float z1 = __uint_as_float(zu & 0xFFFF0000u);
        float m0 = fmaxf(z0 + fmaf(ea, we0, bv0), 0.f) + 1e-7f;
        float m1 = fmaxf(z1 + fmaf(ea, we1, bv1), 0.f) + 1e-7f;
        float p0 = __expf(m0 * tl), p1 = __expf(m1 * tl);
        s0 += ok ? p0 : 0.f; n0 += ok ? p0 * m0 : 0.f;
        s1 += ok ? p1 : 0.f; n1 += ok ? p1 * m1 : 0.f;
    }
    // reduce across the 4 edge-quads (lane bits 4,5)
    s0 += __shfl_xor(s0, 16, 64); n0 += __shfl_xor(n0, 16, 64);
    s1 += __shfl_xor(s1, 16, 64); n1 += __shfl_xor(n1, 16, 64);
    s0 += __shfl_xor(s0, 32, 64); n0 += __shfl_xor(n0, 32, 64);
    s1 += __shfl_xor(s1, 32, 64); n1 += __shfl_xor(n1, 32, 64);
    if (e4 == 0) {
        unsigned r = (unsigned)f2bf(n0 / (s0 + 1e-16f)) |
                     ((unsigned)f2bf(n1 / (s1 + 1e-16f)) << 16);
        aggb[node * 32 + h * 16 + c4] = r;
    }
}

// ---------------- MFMA MLP: block-shared weights in LDS, coalesced epilogue ----------------
__global__ __launch_bounds__(256) void k_mlp(
    const unsigned short* __restrict__ aggb,
    unsigned short* __restrict__ zlo, unsigned short* __restrict__ zhi,
    unsigned short* __restrict__ hb,
    const unsigned short* __restrict__ w1p, const unsigned short* __restrict__ w2p,
    const float* __restrict__ b1,
    const float* __restrict__ g1, const float* __restrict__ be1,
    const float* __restrict__ b2,
    const float* __restrict__ ng, const float* __restrict__ nb, int mode,
    float* __restrict__ pb_sum, float* __restrict__ pb_max) {
    __shared__ unsigned short w1s[8192];
    __shared__ unsigned short w2s[8192];
    __shared__ unsigned short vbuf[4][16 * VB_S];
    __shared__ unsigned short ubuf[4][16 * UB_S];
    __shared__ float lssum[4][4][16], lsmax[4][4][16];
    int lane = threadIdx.x & 63;
    int wave = threadIdx.x >> 6;
    int col = lane & 15, quad = lane >> 4;
    unsigned short* vb = vbuf[wave];
    unsigned short* ub = ubuf[wave];

    {
        const uint4* s1 = (const uint4*)w1p;
        const uint4* s2 = (const uint4*)w2p;
        uint4* d1 = (uint4*)w1s;
        uint4* d2 = (uint4*)w2s;
        #pragma unroll
        for (int i = 0; i < 4; ++i) {
            d1[threadIdx.x + i * 256] = s1[threadIdx.x + i * 256];
            d2[threadIdx.x + i * 256] = s2[threadIdx.x + i * 256];
        }
    }
    __syncthreads();

    float b1f[8], g1f[8], e1f[8];
    #pragma unroll
    for (int t = 0; t < 8; ++t) {
        int ch = t * 16 + col;
        b1f[t] = b1[ch]; g1f[t] = g1[ch]; e1f[t] = be1[ch];
    }
    float b2f_[4], ngf[4], nbf[4];
    #pragma unroll
    for (int t = 0; t < 4; ++t) {
        b2f_[t] = b2[t * 16 + col];
        ngf[t] = ng[t * 16 + col];
        nbf[t] = nb[t * 16 + col];
    }

    float psum[4] = {0.f, 0.f, 0.f, 0.f};
    float pmax[4] = {0.f, 0.f, 0.f, 0.f};
    int nd = lane >> 2;
    int cg = (lane & 3) * 16;
    unsigned short* zhalf = (cg < 32) ? zlo : zhi;   // z split by channel half
    int zoff = cg & 31;

    for (int tile = blockIdx.x * 4 + wave; tile < N_TILES; tile += NB_MLP * 4) {
        int n0 = tile * 16;
        const uint4* ap = (const uint4*)(aggb + (size_t)(n0 + nd) * 64 + cg);
        const uint4* zp = (const uint4*)(zhalf + (size_t)(n0 + nd) * 32 + zoff);
        uint4 a0 = ap[0], a1 = ap[1], z0 = zp[0], z1 = zp[1];
        uint4 r0, r1;
        r0.x = addpk(a0.x, z0.x); r0.y = addpk(a0.y, z0.y);
        r0.z = addpk(a0.z, z0.z); r0.w = addpk(a0.w, z0.w);
        r1.x = addpk(a1.x, z1.x); r1.y = addpk(a1.y, z1.y);
        r1.z = addpk(a1.z, z1.z); r1.w = addpk(a1.w, z1.w);
        uint4* vdst = (uint4*)&vb[nd * VB_S + cg];
        vdst[0] = r0;
        vdst[1] = r1;

        short8 af0 = *(const short8*)&vb[col * VB_S + quad * 8];
        short8 af1 = *(const short8*)&vb[col * VB_S + 32 + quad * 8];

        uint4 h0, h1;
        if (mode >= 1) {
            const uint4* hp = (const uint4*)(hb + (size_t)(n0 + nd) * 64 + cg);
            h0 = hp[0]; h1 = hp[1];
        }

        f32x4 au[8];
        #pragma unroll
        for (int t = 0; t < 8; ++t) {
            short8 w0 = *(const short8*)&w1s[((0 * 8 + t) * 64 + lane) * 8];
            short8 w1 = *(const short8*)&w1s[((1 * 8 + t) * 64 + lane) * 8];
            f32x4 c = {0.f, 0.f, 0.f, 0.f};
            c = __builtin_amdgcn_mfma_f32_16x16x32_bf16(af0, w0, c, 0, 0, 0);
            c = __builtin_amdgcn_mfma_f32_16x16x32_bf16(af1, w1, c, 0, 0, 0);
            au[t] = c;
        }
        #pragma unroll
        for (int r = 0; r < 4; ++r) {
            float sx = 0.f, sq = 0.f;
            #pragma unroll
            for (int t = 0; t < 8; ++t) {
                float v = au[t][r] + b1f[t];
                sx += v; sq += v * v;
            }
            #pragma unroll
            for (int mask = 1; mask < 16; mask <<= 1) {
                sx += __shfl_xor(sx, mask, 64);
                sq += __shfl_xor(sq, mask, 64);
            }
            float mu = sx * (1.f / 128.f);
            float var = sq * (1.f / 128.f) - mu * mu;
            float rs = rsqrtf(var + 1e-5f);
            int row = quad * 4 + r;
            #pragma unroll
            for (int t = 0; t < 8; ++t) {
                float v = au[t][r] + b1f[t];
                float y = fmaxf(fmaf((v - mu) * rs, g1f[t], e1f[t]), 0.f);
                ub[row * UB_S + t * 16 + col] = f2bf(y);
            }
        }
        f32x4 oc[4];
        #pragma unroll
        for (int t = 0; t < 4; ++t) oc[t] = (f32x4){0.f, 0.f, 0.f, 0.f};
        #pragma unroll
        for (int s = 0; s < 4; ++s) {
            short8 a = *(const short8*)&ub[col * UB_S + s * 32 + quad * 8];
            #pragma unroll
            for (int t = 0; t < 4; ++t) {
                short8 w = *(const short8*)&w2s[((s * 4 + t) * 64 + lane) * 8];
                oc[t] = __builtin_amdgcn_mfma_f32_16x16x32_bf16(a, w, oc[t], 0, 0, 0);
            }
        }
        if (mode >= 1) {
            uint4* hdst = (uint4*)&vb[nd * VB_S + cg];
            hdst[0] = h0;
            hdst[1] = h1;
        }
        #pragma unroll
        for (int r = 0; r < 4; ++r) {
            int row = quad * 4 + r;
            float val[4];
            #pragma unroll
            for (int t = 0; t < 4; ++t) {
                val[t] = oc[t][r] + b2f_[t];
                if (mode >= 1) val[t] += bf2f(vb[row * VB_S + t * 16 + col]);
            }
            float sx = 0.f, sq = 0.f;
            #pragma unroll
            for (int t = 0; t < 4; ++t) { sx += val[t]; sq += val[t] * val[t]; }
            #pragma unroll
            for (int mask = 1; mask < 16; mask <<= 1) {
                sx += __shfl_xor(sx, mask, 64);
                sq += __shfl_xor(sq, mask, 64);
            }
            float mu = sx * (1.f / 64.f);
            float var = sq * (1.f / 64.f) - mu * mu;
            float rs = rsqrtf(var + 1e-5f);
            #pragma unroll
            for (int t = 0; t < 4; ++t) {
                float y = fmaxf(fmaf((val[t] - mu) * rs, ngf[t], nbf[t]), 0.f);
                if (mode <= 1) {
                    vb[row * VB_S + t * 16 + col] = f2bf(val[t]);   // h
                    ub[row * UB_S + t * 16 + col] = f2bf(y);        // z
                } else {
                    psum[t] += y;
                    pmax[t] = fmaxf(pmax[t], y);
                }
            }
        }
        if (mode <= 1) {
            const uint4* hsrc = (const uint4*)&vb[nd * VB_S + cg];
            const uint4* zsrc = (const uint4*)&ub[nd * UB_S + cg];
            uint4* hdst = (uint4*)(hb + (size_t)(n0 + nd) * 64 + cg);
            uint4* zdst = (uint4*)(zhalf + (size_t)(n0 + nd) * 32 + zoff);
            hdst[0] = hsrc[0]; hdst[1] = hsrc[1];
            zdst[0] = zsrc[0]; zdst[1] = zsrc[1];
        }
    }
    if (mode == 2) {
        #pragma unroll
        for (int t = 0; t < 4; ++t) {
            psum[t] += __shfl_xor(psum[t], 16, 64);
            psum[t] += __shfl_xor(psum[t], 32, 64);
            pmax[t] = fmaxf(pmax[t], __shfl_xor(pmax[t], 16, 64));
            pmax[t] = fmaxf(pmax[t], __shfl_xor(pmax[t], 32, 64));
        }
        if (quad == 0) {
            #pragma unroll
            for (int t = 0; t < 4; ++t) {
                lssum[wave][t][col] = psum[t];
                lsmax[wave][t][col] = pmax[t];
            }
        }
        __syncthreads();
        if (wave == 0) {
            int t = lane >> 4, c = lane & 15;
            float s = lssum[0][t][c] + lssum[1][t][c] + lssum[2][t][c] + lssum[3][t][c];
            float mx = fmaxf(fmaxf(lsmax[0][t][c], lsmax[1][t][c]),
                             fmaxf(lsmax[2][t][c], lsmax[3][t][c]));
            pb_sum[blockIdx.x * 64 + lane] = s;
            pb_max[blockIdx.x * 64 + lane] = mx;
        }
    }
}

// ---------------- head: full partial reduction + pooling + linear ----------------
__global__ __launch_bounds__(1024) void k_head(
    const float* __restrict__ pb_sum, const float* __restrict__ pb_max,
    const float* __restrict__ Wl, const float* __restrict__ bl, float* __restrict__ out) {
    __shared__ float sa4[16][64], sm4[16][64];
    __shared__ float sa[64], sm[64], emb[64];
    int t = threadIdx.x;
    int ch = t & 63, part = t >> 6;
    float s = 0.f, mx = 0.f;
    for (int b = part; b < NB_MLP; b += 16) {
        s += pb_sum[b * 64 + ch];
        mx = fmaxf(mx, pb_max[b * 64 + ch]);
    }
    sa4[part][ch] = s; sm4[part][ch] = mx;
    __syncthreads();
    if (t < 64) {
        float ss = 0.f, mm = 0.f;
        #pragma unroll
        for (int q = 0; q < 16; ++q) {
            ss += sa4[q][t];
            mm = fmaxf(mm, sm4[q][t]);
        }
        sa[t] = ss; sm[t] = mm;
    }
    __syncthreads();
    if (t < 64) {
        if (t < 32) {
            emb[t] = (sa[2 * t] + sa[2 * t + 1]) * (0.5f / (float)N_NODES);
        } else {
            int i = t - 32;
            emb[t] = fmaxf(sm[2 * i], sm[2 * i + 1]);
        }
    }
    __syncthreads();
    if (t < 64) {
        float acc = bl[t];
        for (int k = 0; k < 64; ++k) acc = fmaf(emb[k], Wl[k * 64 + t], acc);
        out[t] = acc;
    }
}

extern "C" void kernel_launch(void* const* d_in, const int* in_sizes, int n_in,
                              void* d_out, int out_size, void* d_ws, size_t ws_size,
                              hipStream_t stream) {
    const float* x     = (const float*)d_in[0];
    const float* eattr = (const float*)d_in[1];
    const int*   ei    = (const int*)d_in[2];
    const float* Wn    = (const float*)d_in[3];
    const float* bn    = (const float*)d_in[4];
    const float* We    = (const float*)d_in[5];
    const float* be    = (const float*)d_in[6];
    const float* t     = (const float*)d_in[7];
    const float* W1    = (const float*)d_in[8];
    const float* b1    = (const float*)d_in[9];
    const float* lg    = (const float*)d_in[10];
    const float* lb    = (const float*)d_in[11];
    const float* W2    = (const float*)d_in[12];
    const float* b2    = (const float*)d_in[13];
    const float* ng    = (const float*)d_in[14];
    const float* nb    = (const float*)d_in[15];
    const float* Wl    = (const float*)d_in[16];
    const float* bl    = (const float*)d_in[17];
    float* out = (float*)d_out;

    char* p = (char*)d_ws;
    unsigned short* hb  = (unsigned short*)p; p += (size_t)N_NODES * 64 * 2;
    unsigned short* zlo = (unsigned short*)p; p += (size_t)N_NODES * 32 * 2;
    unsigned short* zhi = (unsigned short*)p; p += (size_t)N_NODES * 32 * 2;
    unsigned short* aggb = (unsigned short*)p; p += (size_t)N_NODES * 64 * 2;
    unsigned int* s_pack = (unsigned int*)p; p += (size_t)N_NODES * CAP * 4;
    int* cnt    = (int*)p;  p += (size_t)N_NODES * 4;
    int* gcnt   = (int*)p;  p += (size_t)256 * 4;
    uint2* coarse = (uint2*)p; p += (size_t)NBK * BKCAP * 8;
    float* pb_sum = (float*)p; p += (size_t)NB_MLP * 64 * 4;
    float* pb_max = (float*)p; p += (size_t)NB_MLP * 64 * 4;
    unsigned short* w1p = (unsigned short*)p; p += (size_t)3 * 8192 * 2;
    unsigned short* w2p = (unsigned short*)p; p += (size_t)3 * 8192 * 2;

    hipMemsetAsync(gcnt, 0, (size_t)NBK * sizeof(int), stream);

    k_front<<<NB1 + NB_ENC + NB_WPREP, 256, 0, stream>>>(
        x, Wn, bn, zlo, zhi, W1, W2, w1p, w2p, ei, eattr, gcnt, coarse);
    k_bin2<<<NBK * 2, 256, 0, stream>>>(gcnt, coarse, cnt, s_pack);

    // layer 0
    k_agg<<<NB_AGG, 256, 0, stream>>>(zlo, zhi, cnt, s_pack, We, be, t, 0,
                                      (unsigned int*)aggb);
    k_mlp<<<NB_MLP, 256, 0, stream>>>(aggb, zlo, zhi, hb, w1p, w2p, b1, lg, lb, b2,
                                      ng + 64, nb + 64, 0, pb_sum, pb_max);
    // layer 1
    k_agg<<<NB_AGG, 256, 0, stream>>>(zlo, zhi, cnt, s_pack, We, be, t, 1,
                                      (unsigned int*)aggb);
    k_mlp<<<NB_MLP, 256, 0, stream>>>(aggb, zlo, zhi, hb, w1p + 8192, w2p + 8192,
                                      b1 + 128, lg + 128, lb + 128, b2 + 64,
                                      ng + 128, nb + 128, 1, pb_sum, pb_max);
    // layer 2
    k_agg<<<NB_AGG, 256, 0, stream>>>(zlo, zhi, cnt, s_pack, We, be, t, 2,
                                      (unsigned int*)aggb);
    k_mlp<<<NB_MLP, 256, 0, stream>>>(aggb, zlo, zhi, hb, w1p + 2 * 8192, w2p + 2 * 8192,
                                      b1 + 2 * 128, lg + 2 * 128, lb + 2 * 128, b2 + 2 * 64,
                                      ng, nb, 2, pb_sum, pb_max);

    k_head<<<1, 1024, 0, stream>>>(pb_sum, pb_max, Wl, bl, out);
}

// Round 10
// 297.812 us; speedup vs baseline: 1.5978x; 1.1757x over previous
//
#include <hip/hip_runtime.h>
#include <math.h>

#define N_NODES 50000
#define N_EDGES 1000000
#define HID 64
#define CAP 64                          // slots per node (P(deg>=64) ~ 1e-10 for this input)
#define N_TILES (N_NODES / 16)          // 3125
#define NB_MLP 512                      // mlp blocks (4 waves each, grid-stride)
#define VB_S 72                         // vb row stride (ushorts)
#define UB_S 136                        // ub row stride (ushorts)
#define NB_ENC ((N_NODES + 3) / 4)      // 12500
#define NB_WPREP ((3 * 8192 + 255) / 256) // 96
#define NBK 196                         // coarse buckets = dst>>8 (50000>>8 = 195)
#define BKCAP 6144                      // bucket capacity (mean 5120, +14 sigma)
#define EPB 4096                        // edges per pass-1 block
#define NB1 ((N_EDGES + EPB - 1) / EPB) // 245
static_assert(N_NODES % 16 == 0, "tile math");
static_assert(N_NODES <= 65536, "src must fit in 16 bits");

typedef __attribute__((ext_vector_type(8))) short short8;   // 8 bf16 = 4 VGPRs
typedef __attribute__((ext_vector_type(4))) float f32x4;

__device__ __forceinline__ unsigned short f2bf(float x) {   // RNE float->bf16
    unsigned u = __float_as_uint(x);
    u += 0x7FFFu + ((u >> 16) & 1u);
    return (unsigned short)(u >> 16);
}
__device__ __forceinline__ float bfbits_hi(unsigned pk) {
    return __uint_as_float(pk & 0xFFFF0000u);
}
__device__ __forceinline__ float bf2f(unsigned short v) {
    return __uint_as_float(((unsigned)v) << 16);
}
__device__ __forceinline__ unsigned addpk(unsigned a, unsigned b) {
    float lo = __uint_as_float(a << 16) + __uint_as_float(b << 16);
    float hi = __uint_as_float(a & 0xFFFF0000u) + __uint_as_float(b & 0xFFFF0000u);
    return (unsigned)f2bf(lo) | ((unsigned)f2bf(hi) << 16);
}

// ---------------- fused front: node encoder | weight prep ----------------
__global__ __launch_bounds__(256) void k_front(
    const float* __restrict__ x, const float* __restrict__ Wn,
    const float* __restrict__ bn, unsigned short* __restrict__ zb,
    const float* __restrict__ W1, const float* __restrict__ W2,
    unsigned short* __restrict__ w1p, unsigned short* __restrict__ w2p) {
    int b = blockIdx.x;
    if (b < NB_ENC) {
        // node encoder: zb = bf16(x @ W_node + b_node)
        int n = b * 4 + (threadIdx.x >> 6);
        int c = threadIdx.x & 63;
        if (n >= N_NODES) return;
        float acc = bn[c];
        const float* xr = x + n * 16;
        #pragma unroll
        for (int k = 0; k < 16; ++k) acc = fmaf(xr[k], Wn[k * 64 + c], acc);
        zb[n * 64 + c] = f2bf(acc);
    } else {
        // weight prep: pack W1/W2 (3 layers) into bf16 fragment order
        int i = (b - NB_ENC) * 256 + threadIdx.x;
        if (i >= 3 * 8192) return;
        int L = i >> 13, r = i & 8191;
        int j = r & 7, lane = (r >> 3) & 63;
        int quad = lane >> 4, col = lane & 15;
        {
            int st = r >> 9;                 // s=st>>3 (2), t=st&7 (8)
            int s = st >> 3, t = st & 7;
            w1p[i] = f2bf(W1[L * 8192 + (s * 32 + quad * 8 + j) * 128 + t * 16 + col]);
        }
        {
            int ft = r >> 9;                 // s=ft>>2 (4), t=ft&3 (4)
            int s = ft >> 2, t = ft & 3;
            w2p[i] = f2bf(W2[L * 8192 + (s * 32 + quad * 8 + j) * 64 + t * 16 + col]);
        }
    }
}

// ---------------- pass 1: LDS-binned coarse scatter (dst>>8 buckets) ----------------
__global__ __launch_bounds__(256) void k_bin1(
    const int* __restrict__ ei, const float* __restrict__ eattr,
    int* __restrict__ gcnt, uint2* __restrict__ coarse) {
    __shared__ unsigned pk_l[EPB];          // 16 KB
    __shared__ unsigned short dst_l[EPB];   // 8 KB
    __shared__ unsigned spk[EPB];           // 16 KB (bucket-sorted)
    __shared__ unsigned short sdst[EPB];    // 8 KB
    __shared__ int hist[NBK], loc[NBK], gbase[NBK], cur[NBK];
    __shared__ int inc[256];
    int tid = threadIdx.x;
    int e0 = blockIdx.x * EPB;
    int nel = N_EDGES - e0; if (nel > EPB) nel = EPB;
    for (int b = tid; b < NBK; b += 256) { hist[b] = 0; cur[b] = 0; }
    __syncthreads();
    for (int j = tid; j < nel; j += 256) {
        int i = e0 + j;
        int d = ei[N_EDGES + i];
        unsigned pk = ((unsigned)f2bf(eattr[i]) << 16) | (unsigned)(ei[i] & 0xFFFF);
        pk_l[j] = pk; dst_l[j] = (unsigned short)d;
        atomicAdd(&hist[d >> 8], 1);
    }
    __syncthreads();
    int v = (tid < NBK) ? hist[tid] : 0;
    inc[tid] = v;
    __syncthreads();
    #pragma unroll
    for (int dd = 1; dd < 256; dd <<= 1) {
        int t2 = (tid >= dd) ? inc[tid - dd] : 0;
        __syncthreads();
        inc[tid] += t2;
        __syncthreads();
    }
    if (tid < NBK) {
        loc[tid] = inc[tid] - v;                     // exclusive local offset
        gbase[tid] = atomicAdd(&gcnt[tid], v);       // reserve bucket space
    }
    __syncthreads();
    // local counting sort by bucket
    for (int j = tid; j < nel; j += 256) {
        int bkt = dst_l[j] >> 8;
        int r = atomicAdd(&cur[bkt], 1);
        int pos = loc[bkt] + r;
        spk[pos] = pk_l[j]; sdst[pos] = dst_l[j];
    }
    __syncthreads();
    // write out: consecutive j within a bucket run -> consecutive global addresses
    for (int j = tid; j < nel; j += 256) {
        int d = sdst[j];
        int bkt = d >> 8;
        int off = gbase[bkt] + (j - loc[bkt]);
        if (off < BKCAP) coarse[(size_t)bkt * BKCAP + off] = make_uint2(spk[j], (unsigned)d);
    }
}

// ---------------- pass 2: per-bucket fine CSR built in LDS -> CAP-slotted s_pack ----------------
__global__ __launch_bounds__(256) void k_bin2(
    const int* __restrict__ gcnt, const uint2* __restrict__ coarse,
    int* __restrict__ cnt, unsigned int* __restrict__ s_pack) {
    __shared__ unsigned epk[BKCAP];          // 24 KB
    __shared__ unsigned char eln[BKCAP];     // 6 KB
    __shared__ unsigned spk[BKCAP];          // 24 KB (node-sorted)
    __shared__ unsigned char sln[BKCAP];     // 6 KB
    __shared__ int hist[256], cur[256], inc2[256];   // hist reused as loc after scan
    int tid = threadIdx.x;
    int b = blockIdx.x;
    int m = gcnt[b]; if (m > BKCAP) m = BKCAP;
    hist[tid] = 0; cur[tid] = 0;
    __syncthreads();
    for (int j = tid; j < m; j += 256) {
        uint2 e = coarse[(size_t)b * BKCAP + j];
        epk[j] = e.x;
        int ln = (int)(e.y & 255u);
        eln[j] = (unsigned char)ln;
        atomicAdd(&hist[ln], 1);
    }
    __syncthreads();
    int v = hist[tid];
    inc2[tid] = v;
    __syncthreads();
    #pragma unroll
    for (int dd = 1; dd < 256; dd <<= 1) {
        int t2 = (tid >= dd) ? inc2[tid - dd] : 0;
        __syncthreads();
        inc2[tid] += t2;
        __syncthreads();
    }
    int lv = inc2[tid] - v;                  // exclusive
    __syncthreads();
    hist[tid] = lv;                          // hist[] now holds loc[]
    int node = b * 256 + tid;
    if (node < N_NODES) cnt[node] = v;
    __syncthreads();
    for (int j = tid; j < m; j += 256) {
        int ln = eln[j];
        int r = atomicAdd(&cur[ln], 1);
        int pos = hist[ln] + r;
        spk[pos] = epk[j]; sln[pos] = (unsigned char)ln;
    }
    __syncthreads();
    for (int j = tid; j < m; j += 256) {
        int ln = sln[j];
        int k = j - hist[ln];
        if (k < CAP) s_pack[(size_t)(b * 256 + ln) * CAP + k] = spk[j];
    }
}

// ---------------- softmax aggregation (shift-free), one wave/node, 8-edge ILP ----------------
// lanes 0-31: even edge, lanes 32-63: odd edge; each lane owns channels {2c2, 2c2+1}
__global__ __launch_bounds__(256) void k_agg(
    const unsigned short* __restrict__ zb, const int* __restrict__ cnt,
    const unsigned int* __restrict__ s_pack,
    const float* __restrict__ We, const float* __restrict__ be,
    const float* __restrict__ t, int layer, unsigned short* __restrict__ aggb) {
    int wid = (blockIdx.x * blockDim.x + threadIdx.x) >> 6;
    int lane = threadIdx.x & 63;
    if (wid >= N_NODES) return;
    int deg = cnt[wid];
    deg = (deg < CAP) ? deg : CAP;
    int beg = wid * CAP, end = beg + deg;
    int half = lane >> 5;          // 0: even edge of pair, 1: odd edge
    int c2 = lane & 31;            // uint index in row; channels 2c2, 2c2+1
    float we0 = We[2 * c2], we1 = We[2 * c2 + 1];
    float bv0 = be[2 * c2], bv1 = be[2 * c2 + 1];
    float tl = t[layer];
    const unsigned* zbu = (const unsigned*)zb;
    float s0 = 0.f, s1 = 0.f, n0 = 0.f, n1 = 0.f;
    int i = beg;
    for (; i + 7 < end; i += 8) {
        unsigned pk[4];
        #pragma unroll
        for (int j = 0; j < 4; ++j) {
            unsigned pa = s_pack[i + 2 * j];       // wave-uniform -> scalar path
            unsigned pb = s_pack[i + 2 * j + 1];
            pk[j] = half ? pb : pa;
        }
        unsigned zu[4];
        #pragma unroll
        for (int j = 0; j < 4; ++j) zu[j] = zbu[(pk[j] & 0xFFFFu) * 32 + c2];
        #pragma unroll
        for (int j = 0; j < 4; ++j) {
            float ea = bfbits_hi(pk[j]);
            float z0 = __uint_as_float(zu[j] << 16);
            float z1 = __uint_as_float(zu[j] & 0xFFFF0000u);
            float m0 = fmaxf(z0 + fmaf(ea, we0, bv0), 0.f) + 1e-7f;
            float m1 = fmaxf(z1 + fmaf(ea, we1, bv1), 0.f) + 1e-7f;
            float p0 = __expf(m0 * tl), p1 = __expf(m1 * tl);
            s0 += p0; n0 = fmaf(p0, m0, n0);
            s1 += p1; n1 = fmaf(p1, m1, n1);
        }
    }
    for (; i + 1 < end; i += 2) {
        unsigned pa = s_pack[i], pb = s_pack[i + 1];
        unsigned pk = half ? pb : pa;
        unsigned zu = zbu[(pk & 0xFFFFu) * 32 + c2];
        float ea = bfbits_hi(pk);
        float z0 = __uint_as_float(zu << 16);
        float z1 = __uint_as_float(zu & 0xFFFF0000u);
        float m0 = fmaxf(z0 + fmaf(ea, we0, bv0), 0.f) + 1e-7f;
        float m1 = fmaxf(z1 + fmaf(ea, we1, bv1), 0.f) + 1e-7f;
        float p0 = __expf(m0 * tl), p1 = __expf(m1 * tl);
        s0 += p0; n0 = fmaf(p0, m0, n0);
        s1 += p1; n1 = fmaf(p1, m1, n1);
    }
    if (i < end) {                 // single leftover edge: lo half only
        unsigned pk = s_pack[i];
        unsigned zu = zbu[(pk & 0xFFFFu) * 32 + c2];
        float ea = bfbits_hi(pk);
        float z0 = __uint_as_float(zu << 16);
        float z1 = __uint_as_float(zu & 0xFFFF0000u);
        float m0 = fmaxf(z0 + fmaf(ea, we0, bv0), 0.f) + 1e-7f;
        float m1 = fmaxf(z1 + fmaf(ea, we1, bv1), 0.f) + 1e-7f;
        float p0 = __expf(m0 * tl), p1 = __expf(m1 * tl);
        if (half == 0) {
            s0 += p0; n0 = fmaf(p0, m0, n0);
            s1 += p1; n1 = fmaf(p1, m1, n1);
        }
    }
    // combine even/odd halves
    s0 += __shfl_xor(s0, 32, 64); n0 += __shfl_xor(n0, 32, 64);
    s1 += __shfl_xor(s1, 32, 64); n1 += __shfl_xor(n1, 32, 64);
    if (half == 0) {
        unsigned r = (unsigned)f2bf(n0 / (s0 + 1e-16f)) |
                     ((unsigned)f2bf(n1 / (s1 + 1e-16f)) << 16);
        ((unsigned*)aggb)[wid * 32 + c2] = r;
    }
}

// ---------------- MFMA MLP: block-shared weights in LDS, coalesced epilogue ----------------
__global__ __launch_bounds__(256) void k_mlp(
    const unsigned short* __restrict__ aggb, unsigned short* __restrict__ zb,
    unsigned short* __restrict__ hb,
    const unsigned short* __restrict__ w1p, const unsigned short* __restrict__ w2p,
    const float* __restrict__ b1,
    const float* __restrict__ g1, const float* __restrict__ be1,
    const float* __restrict__ b2,
    const float* __restrict__ ng, const float* __restrict__ nb, int mode,
    float* __restrict__ pb_sum, float* __restrict__ pb_max) {
    __shared__ unsigned short w1s[8192];
    __shared__ unsigned short w2s[8192];
    __shared__ unsigned short vbuf[4][16 * VB_S];
    __shared__ unsigned short ubuf[4][16 * UB_S];
    __shared__ float lssum[4][4][16], lsmax[4][4][16];
    int lane = threadIdx.x & 63;
    int wave = threadIdx.x >> 6;
    int col = lane & 15, quad = lane >> 4;
    unsigned short* vb = vbuf[wave];
    unsigned short* ub = ubuf[wave];

    {
        const uint4* s1 = (const uint4*)w1p;
        const uint4* s2 = (const uint4*)w2p;
        uint4* d1 = (uint4*)w1s;
        uint4* d2 = (uint4*)w2s;
        #pragma unroll
        for (int i = 0; i < 4; ++i) {
            d1[threadIdx.x + i * 256] = s1[threadIdx.x + i * 256];
            d2[threadIdx.x + i * 256] = s2[threadIdx.x + i * 256];
        }
    }
    __syncthreads();

    float b1f[8], g1f[8], e1f[8];
    #pragma unroll
    for (int t = 0; t < 8; ++t) {
        int ch = t * 16 + col;
        b1f[t] = b1[ch]; g1f[t] = g1[ch]; e1f[t] = be1[ch];
    }
    float b2f_[4], ngf[4], nbf[4];
    #pragma unroll
    for (int t = 0; t < 4; ++t) {
        b2f_[t] = b2[t * 16 + col];
        ngf[t] = ng[t * 16 + col];
        nbf[t] = nb[t * 16 + col];
    }

    float psum[4] = {0.f, 0.f, 0.f, 0.f};
    float pmax[4] = {0.f, 0.f, 0.f, 0.f};
    int nd = lane >> 2;
    int cg = (lane & 3) * 16;

    for (int tile = blockIdx.x * 4 + wave; tile < N_TILES; tile += NB_MLP * 4) {
        int n0 = tile * 16;
        const uint4* ap = (const uint4*)(aggb + (size_t)(n0 + nd) * 64 + cg);
        const uint4* zp = (const uint4*)(zb + (size_t)(n0 + nd) * 64 + cg);
        uint4 a0 = ap[0], a1 = ap[1], z0 = zp[0], z1 = zp[1];
        uint4 r0, r1;
        r0.x = addpk(a0.x, z0.x); r0.y = addpk(a0.y, z0.y);
        r0.z = addpk(a0.z, z0.z); r0.w = addpk(a0.w, z0.w);
        r1.x = addpk(a1.x, z1.x); r1.y = addpk(a1.y, z1.y);
        r1.z = addpk(a1.z, z1.z); r1.w = addpk(a1.w, z1.w);
        uint4* vdst = (uint4*)&vb[nd * VB_S + cg];
        vdst[0] = r0;
        vdst[1] = r1;

        short8 af0 = *(const short8*)&vb[col * VB_S + quad * 8];
        short8 af1 = *(const short8*)&vb[col * VB_S + 32 + quad * 8];

        uint4 h0, h1;
        if (mode >= 1) {
            const uint4* hp = (const uint4*)(hb + (size_t)(n0 + nd) * 64 + cg);
            h0 = hp[0]; h1 = hp[1];
        }

        f32x4 au[8];
        #pragma unroll
        for (int t = 0; t < 8; ++t) {
            short8 w0 = *(const short8*)&w1s[((0 * 8 + t) * 64 + lane) * 8];
            short8 w1 = *(const short8*)&w1s[((1 * 8 + t) * 64 + lane) * 8];
            f32x4 c = {0.f, 0.f, 0.f, 0.f};
            c = __builtin_amdgcn_mfma_f32_16x16x32_bf16(af0, w0, c, 0, 0, 0);
            c = __builtin_amdgcn_mfma_f32_16x16x32_bf16(af1, w1, c, 0, 0, 0);
            au[t] = c;
        }
        #pragma unroll
        for (int r = 0; r < 4; ++r) {
            float sx = 0.f, sq = 0.f;
            #pragma unroll
            for (int t = 0; t < 8; ++t) {
                float v = au[t][r] + b1f[t];
                sx += v; sq += v * v;
            }
            #pragma unroll
            for (int mask = 1; mask < 16; mask <<= 1) {
                sx += __shfl_xor(sx, mask, 64);
                sq += __shfl_xor(sq, mask, 64);
            }
            float mu = sx * (1.f / 128.f);
            float var = sq * (1.f / 128.f) - mu * mu;
            float rs = rsqrtf(var + 1e-5f);
            int row = quad * 4 + r;
            #pragma unroll
            for (int t = 0; t < 8; ++t) {
                float v = au[t][r] + b1f[t];
                float y = fmaxf(fmaf((v - mu) * rs, g1f[t], e1f[t]), 0.f);
                ub[row * UB_S + t * 16 + col] = f2bf(y);
            }
        }
        f32x4 oc[4];
        #pragma unroll
        for (int t = 0; t < 4; ++t) oc[t] = (f32x4){0.f, 0.f, 0.f, 0.f};
        #pragma unroll
        for (int s = 0; s < 4; ++s) {
            short8 a = *(const short8*)&ub[col * UB_S + s * 32 + quad * 8];
            #pragma unroll
            for (int t = 0; t < 4; ++t) {
                short8 w = *(const short8*)&w2s[((s * 4 + t) * 64 + lane) * 8];
                oc[t] = __builtin_amdgcn_mfma_f32_16x16x32_bf16(a, w, oc[t], 0, 0, 0);
            }
        }
        if (mode >= 1) {
            uint4* hdst = (uint4*)&vb[nd * VB_S + cg];
            hdst[0] = h0;
            hdst[1] = h1;
        }
        #pragma unroll
        for (int r = 0; r < 4; ++r) {
            int row = quad * 4 + r;
            float val[4];
            #pragma unroll
            for (int t = 0; t < 4; ++t) {
                val[t] = oc[t][r] + b2f_[t];
                if (mode >= 1) val[t] += bf2f(vb[row * VB_S + t * 16 + col]);
            }
            float sx = 0.f, sq = 0.f;
            #pragma unroll
            for (int t = 0; t < 4; ++t) { sx += val[t]; sq += val[t] * val[t]; }
            #pragma unroll
            for (int mask = 1; mask < 16; mask <<= 1) {
                sx += __shfl_xor(sx, mask, 64);
                sq += __shfl_xor(sq, mask, 64);
            }
            float mu = sx * (1.f / 64.f);
            float var = sq * (1.f / 64.f) - mu * mu;
            float rs = rsqrtf(var + 1e-5f);
            #pragma unroll
            for (int t = 0; t < 4; ++t) {
                float y = fmaxf(fmaf((val[t] - mu) * rs, ngf[t], nbf[t]), 0.f);
                if (mode <= 1) {
                    vb[row * VB_S + t * 16 + col] = f2bf(val[t]);   // h
                    ub[row * UB_S + t * 16 + col] = f2bf(y);        // z
                } else {
                    psum[t] += y;
                    pmax[t] = fmaxf(pmax[t], y);
                }
            }
        }
        if (mode <= 1) {
            const uint4* hsrc = (const uint4*)&vb[nd * VB_S + cg];
            const uint4* zsrc = (const uint4*)&ub[nd * UB_S + cg];
            uint4* hdst = (uint4*)(hb + (size_t)(n0 + nd) * 64 + cg);
            uint4* zdst = (uint4*)(zb + (size_t)(n0 + nd) * 64 + cg);
            hdst[0] = hsrc[0]; hdst[1] = hsrc[1];
            zdst[0] = zsrc[0]; zdst[1] = zsrc[1];
        }
    }
    if (mode == 2) {
        #pragma unroll
        for (int t = 0; t < 4; ++t) {
            psum[t] += __shfl_xor(psum[t], 16, 64);
            psum[t] += __shfl_xor(psum[t], 32, 64);
            pmax[t] = fmaxf(pmax[t], __shfl_xor(pmax[t], 16, 64));
            pmax[t] = fmaxf(pmax[t], __shfl_xor(pmax[t], 32, 64));
        }
        if (quad == 0) {
            #pragma unroll
            for (int t = 0; t < 4; ++t) {
                lssum[wave][t][col] = psum[t];
                lsmax[wave][t][col] = pmax[t];
            }
        }
        __syncthreads();
        if (wave == 0) {
            int t = lane >> 4, c = lane & 15;
            float s = lssum[0][t][c] + lssum[1][t][c] + lssum[2][t][c] + lssum[3][t][c];
            float mx = fmaxf(fmaxf(lsmax[0][t][c], lsmax[1][t][c]),
                             fmaxf(lsmax[2][t][c], lsmax[3][t][c]));
            pb_sum[blockIdx.x * 64 + lane] = s;
            pb_max[blockIdx.x * 64 + lane] = mx;
        }
    }
}

// ---------------- head: full partial reduction + pooling + linear ----------------
__global__ __launch_bounds__(1024) void k_head(
    const float* __restrict__ pb_sum, const float* __restrict__ pb_max,
    const float* __restrict__ Wl, const float* __restrict__ bl, float* __restrict__ out) {
    __shared__ float sa4[16][64], sm4[16][64];
    __shared__ float sa[64], sm[64], emb[64];
    int t = threadIdx.x;
    int ch = t & 63, part = t >> 6;
    float s = 0.f, mx = 0.f;
    for (int b = part; b < NB_MLP; b += 16) {
        s += pb_sum[b * 64 + ch];
        mx = fmaxf(mx, pb_max[b * 64 + ch]);
    }
    sa4[part][ch] = s; sm4[part][ch] = mx;
    __syncthreads();
    if (t < 64) {
        float ss = 0.f, mm = 0.f;
        #pragma unroll
        for (int q = 0; q < 16; ++q) {
            ss += sa4[q][t];
            mm = fmaxf(mm, sm4[q][t]);
        }
        sa[t] = ss; sm[t] = mm;
    }
    __syncthreads();
    if (t < 64) {
        if (t < 32) {
            emb[t] = (sa[2 * t] + sa[2 * t + 1]) * (0.5f / (float)N_NODES);
        } else {
            int i = t - 32;
            emb[t] = fmaxf(sm[2 * i], sm[2 * i + 1]);
        }
    }
    __syncthreads();
    if (t < 64) {
        float acc = bl[t];
        for (int k = 0; k < 64; ++k) acc = fmaf(emb[k], Wl[k * 64 + t], acc);
        out[t] = acc;
    }
}

extern "C" void kernel_launch(void* const* d_in, const int* in_sizes, int n_in,
                              void* d_out, int out_size, void* d_ws, size_t ws_size,
                              hipStream_t stream) {
    const float* x     = (const float*)d_in[0];
    const float* eattr = (const float*)d_in[1];
    const int*   ei    = (const int*)d_in[2];
    const float* Wn    = (const float*)d_in[3];
    const float* bn    = (const float*)d_in[4];
    const float* We    = (const float*)d_in[5];
    const float* be    = (const float*)d_in[6];
    const float* t     = (const float*)d_in[7];
    const float* W1    = (const float*)d_in[8];
    const float* b1    = (const float*)d_in[9];
    const float* lg    = (const float*)d_in[10];
    const float* lb    = (const float*)d_in[11];
    const float* W2    = (const float*)d_in[12];
    const float* b2    = (const float*)d_in[13];
    const float* ng    = (const float*)d_in[14];
    const float* nb    = (const float*)d_in[15];
    const float* Wl    = (const float*)d_in[16];
    const float* bl    = (const float*)d_in[17];
    float* out = (float*)d_out;

    char* p = (char*)d_ws;
    unsigned short* hb   = (unsigned short*)p; p += (size_t)N_NODES * 64 * 2;
    unsigned short* zb   = (unsigned short*)p; p += (size_t)N_NODES * 64 * 2;
    unsigned short* aggb = (unsigned short*)p; p += (size_t)N_NODES * 64 * 2;
    unsigned int* s_pack = (unsigned int*)p; p += (size_t)N_NODES * CAP * 4;
    int* cnt    = (int*)p;  p += (size_t)N_NODES * 4;
    int* gcnt   = (int*)p;  p += (size_t)256 * 4;
    uint2* coarse = (uint2*)p; p += (size_t)NBK * BKCAP * 8;
    float* pb_sum = (float*)p; p += (size_t)NB_MLP * 64 * 4;
    float* pb_max = (float*)p; p += (size_t)NB_MLP * 64 * 4;
    unsigned short* w1p = (unsigned short*)p; p += (size_t)3 * 8192 * 2;
    unsigned short* w2p = (unsigned short*)p; p += (size_t)3 * 8192 * 2;

    hipMemsetAsync(gcnt, 0, (size_t)NBK * sizeof(int), stream);

    k_front<<<NB_ENC + NB_WPREP, 256, 0, stream>>>(x, Wn, bn, zb, W1, W2, w1p, w2p);
    k_bin1<<<NB1, 256, 0, stream>>>(ei, eattr, gcnt, coarse);
    k_bin2<<<NBK, 256, 0, stream>>>(gcnt, coarse, cnt, s_pack);

    // layer 0
    k_agg<<<(N_NODES + 3) / 4, 256, 0, stream>>>(zb, cnt, s_pack, We, be, t, 0, aggb);
    k_mlp<<<NB_MLP, 256, 0, stream>>>(aggb, zb, hb, w1p, w2p, b1, lg, lb, b2,
                                      ng + 64, nb + 64, 0, pb_sum, pb_max);
    // layer 1
    k_agg<<<(N_NODES + 3) / 4, 256, 0, stream>>>(zb, cnt, s_pack, We, be, t, 1, aggb);
    k_mlp<<<NB_MLP, 256, 0, stream>>>(aggb, zb, hb, w1p + 8192, w2p + 8192,
                                      b1 + 128, lg + 128, lb + 128, b2 + 64,
                                      ng + 128, nb + 128, 1, pb_sum, pb_max);
    // layer 2
    k_agg<<<(N_NODES + 3) / 4, 256, 0, stream>>>(zb, cnt, s_pack, We, be, t, 2, aggb);
    k_mlp<<<NB_MLP, 256, 0, stream>>>(aggb, zb, hb, w1p + 2 * 8192, w2p + 2 * 8192,
                                      b1 + 2 * 128, lg + 2 * 128, lb + 2 * 128, b2 + 2 * 64,
                                      ng, nb, 2, pb_sum, pb_max);

    k_head<<<1, 1024, 0, stream>>>(pb_sum, pb_max, Wl, bl, out);
}